// Round 17
// baseline (522.374 us; speedup 1.0000x reference)
//
#include <hip/hip_runtime.h>
#include <math.h>

#define N_ 256
#define L_ 20
#define B_ 10
#define D_ 128
#define H_ 128
#define ASP_ 4
#define KK_ 16
#define NIT_ 20000
#define H2_ 256
#define G4_ 1024
#define LBD_ 25600
#define NL_ 5120
#define NLB_ 51200

typedef __attribute__((ext_vector_type(8))) short bf16x8;
typedef __attribute__((ext_vector_type(4))) short bf16x4;
typedef __attribute__((ext_vector_type(4))) float f32x4;

__device__ __forceinline__ float sigf_fast(float x){
  return __builtin_amdgcn_rcpf(1.0f + __expf(-x));
}
__device__ __forceinline__ float tanh_fast(float x){
  return 1.0f - 2.0f*__builtin_amdgcn_rcpf(__expf(2.0f*x) + 1.0f);
}
__device__ __forceinline__ unsigned short f2b(float f){
  unsigned int u = __float_as_uint(f);
  unsigned int r = (u + 0x7FFFu + ((u>>16)&1u)) >> 16;   // RNE
  return (unsigned short)r;
}
__device__ __forceinline__ float b2f(unsigned short b){
  return __uint_as_float(((unsigned int)b) << 16);
}

// ---------------- gather: embs[n,l,b,:] = itemEmb[seq[n,l,b],:] (+ bf16 shadow) ----------------
__global__ void k_gather(const int* __restrict__ seq, const float* __restrict__ itemEmb,
                         float* __restrict__ embs, unsigned short* __restrict__ ebh){
  int row = blockIdx.x;          // 0..51199 = (n,l,b)
  int t = threadIdx.x;           // 0..127
  int idx = seq[row];
  float v = itemEmb[idx*D_ + t];
  embs[row*D_ + t] = v;
  ebh[row*D_ + t] = f2b(v);
}

// ---------------- fc1: u[n] = dot(embs[n,:], fc1_w) + fc1_b ----------------
__global__ void k_fc1(const float* __restrict__ embs, const float* __restrict__ w,
                      const float* __restrict__ b, float* __restrict__ u){
  int n = blockIdx.x; int t = threadIdx.x;
  float s = 0.f;
  for (int i = t; i < LBD_; i += 256) s += embs[n*LBD_+i]*w[i];
  __shared__ float red[256];
  red[t]=s; __syncthreads();
  for (int o=128;o>0;o>>=1){ if(t<o) red[t]+=red[t+o]; __syncthreads(); }
  if(t==0) u[n]=red[0]+b[0];
}

// ---------------- fused uA + sq: ua=tanh(tanh(u*proju)); sq=sum_h ua^2 (libm: kNN path) ----------------
__global__ void k_uasq(const float* __restrict__ u, const float* __restrict__ proju,
                       float* __restrict__ ua, float* __restrict__ sq){
  int an = blockIdx.x;           // a*N_+n
  int h = threadIdx.x;           // 128
  int a = an / N_, n = an % N_;
  float v = tanhf(tanhf(u[n]*proju[a*H_+h]));
  ua[an*H_ + h] = v;
  __shared__ float red[128];
  red[h] = v*v; __syncthreads();
  for(int o=64;o>0;o>>=1){ if(h<o) red[h]+=red[h+o]; __syncthreads(); }
  if(h==0) sq[an]=red[0];
}

// ---------------- fused dist + top-16: row in LDS, wave-0 selection (bit-identical) ----------------
__global__ __launch_bounds__(256) void k_disttopk(const float* __restrict__ ua,
    const float* __restrict__ sq, int* __restrict__ nbr){
  int n = blockIdx.x, a = blockIdx.y, m = threadIdx.x;  // 256 threads
  __shared__ float un[H_];
  __shared__ float row[N_];
  if(m < H_) un[m] = ua[(a*N_+n)*H_ + m];
  __syncthreads();
  const float* um = &ua[(a*N_+m)*H_];
  float dot=0.f;
  for(int h=0;h<H_;h++) dot += un[h]*um[h];
  float dval = sq[a*N_+n] + sq[a*N_+m] - 2.f*dot;
  if(m==n) dval = -1.0f;
  row[m] = dval;
  __syncthreads();
  if(m < 64){
    int lane = m;
    int wid = a*N_+n;
    float v[4]; int idx[4];
    #pragma unroll
    for(int j=0;j<4;j++){ int mm = lane*4 + j; v[j] = row[mm]; idx[j] = mm; }
    for(int k=0;k<KK_;k++){
      float bv = v[0]; int bi = idx[0];
      #pragma unroll
      for(int j=1;j<4;j++)
        if(v[j] < bv || (v[j]==bv && idx[j] < bi)){ bv=v[j]; bi=idx[j]; }
      float rv = bv; int ri = bi;
      #pragma unroll
      for(int o=32;o>0;o>>=1){
        float ov = __shfl_xor(rv, o, 64);
        int   oi = __shfl_xor(ri, o, 64);
        if(ov < rv || (ov==rv && oi < ri)){ rv=ov; ri=oi; }
      }
      if((ri>>2) == lane){ v[ri&3] = 3.4e38f; idx[ri&3] = 0x7fffffff; }
      if(k>0 && lane==0) nbr[wid*(KK_-1)+(k-1)] = ri;
    }
  }
}

// ---------------- EB[n,l,d] = sum_b embs ----------------
__global__ void k_eb(const float* __restrict__ embs, float* __restrict__ eb){
  int nl = blockIdx.x; int d = threadIdx.x;
  float s=0.f;
  const float* p = &embs[nl*B_*D_ + d];
  for(int b=0;b<B_;b++) s += p[b*D_];
  eb[nl*D_ + d] = s;
}

// ---------------- fused prep: LSTM weight permutes (fp32+bf16) + biases + projb ----------------
// segments: [0,262144) wp0 | [262144,524288) whb0 | [524288,786432) wp1 |
//           [786432,1048576) whb1 | [1048576,1114112) projb | [1114112,1115136) bp0 |
//           [1115136,1116160) bp1
__global__ void k_prep(const float* __restrict__ wih0, const float* __restrict__ whh0,
                       const float* __restrict__ wih1, const float* __restrict__ whh1,
                       const float* __restrict__ bih0, const float* __restrict__ bhh0,
                       const float* __restrict__ bih1, const float* __restrict__ bhh1,
                       const float* __restrict__ proji,
                       float* __restrict__ wp0, unsigned short* __restrict__ whb0,
                       float* __restrict__ wp1, unsigned short* __restrict__ whb1,
                       float* __restrict__ bp0, float* __restrict__ bp1,
                       unsigned short* __restrict__ projb){
  int i = blockIdx.x*blockDim.x + threadIdx.x;
  if(i < 262144){
    int k=i%H2_, j=i/H2_, g=j/H2_, jj=j%H2_;
    wp0[(jj*4+g)*H2_+k] = wih0[i];
  } else if(i < 524288){
    int e=i-262144; int k=e%H2_, j=e/H2_, g=j/H2_, jj=j%H2_;
    whb0[(jj*4+g)*H2_+k] = f2b(whh0[e]);
  } else if(i < 786432){
    int e=i-524288; int k=e%H2_, j=e/H2_, g=j/H2_, jj=j%H2_;
    wp1[(jj*4+g)*H2_+k] = wih1[e];
  } else if(i < 1048576){
    int e=i-786432; int k=e%H2_, j=e/H2_, g=j/H2_, jj=j%H2_;
    whb1[(jj*4+g)*H2_+k] = f2b(whh1[e]);
  } else if(i < 1114112){
    int e=i-1048576; int h=e%H_, d=(e/H_)%D_, aa=e/(D_*H_);
    projb[(aa*H_+h)*D_+d] = f2b(proji[e]);
  } else if(i < 1115136){
    int j=i-1114112; int g=j/H2_, jj=j%H2_;
    bp0[jj*4+g] = bih0[j] + bhh0[j];
  } else if(i < 1116160){
    int j=i-1115136; int g=j/H2_, jj=j%H2_;
    bp1[jj*4+g] = bih1[j] + bhh1[j];
  }
}

// ---------------- fused UI stage: MFMA bf16 GEMM + tanh^2 + sum_b -> na[.., 0:128] ----------------
__global__ __launch_bounds__(256) void k_uimm(const unsigned short* __restrict__ ebh,
                                              const unsigned short* __restrict__ projb,
                                              float* __restrict__ na){
  __shared__ char smem[53248];
  unsigned short* As = (unsigned short*)smem;            // 80x128 bf16, swizzled 16B chunks
  unsigned short* Bs = (unsigned short*)(smem + 20480);  // 128x128 bf16, swizzled
  float*          Cs = (float*)smem;                     // 80x128 f32 (aliases As+Bs later)

  int mb = blockIdx.x;   // 0..639
  int a  = blockIdx.y;   // 0..3
  int tid = threadIdx.x;

  const unsigned short* asrc = ebh + (size_t)mb*10240;
  #pragma unroll
  for(int t=0;t<5;t++){
    int c = tid + t*256;
    int row = c >> 4;
    *(bf16x8*)(As + 8*(c ^ (row&7))) = *(const bf16x8*)(asrc + 8*c);
  }
  const unsigned short* bsrc = projb + a*16384;
  #pragma unroll
  for(int t=0;t<8;t++){
    int c = tid + t*256;
    int row = c >> 4;
    *(bf16x8*)(Bs + 8*(c ^ (row&7))) = *(const bf16x8*)(bsrc + 8*c);
  }
  __syncthreads();

  int lane = tid & 63, wave = tid >> 6;
  int l15 = lane & 15, l4 = lane >> 4;
  f32x4 acc[5][2] = {};
  #pragma unroll
  for(int kk=0;kk<4;kk++){
    bf16x8 bfr[2];
    #pragma unroll
    for(int tc=0;tc<2;tc++){
      int h = (wave*2+tc)*16 + l15;
      int c = h*16 + kk*4 + l4;
      bfr[tc] = *(const bf16x8*)(Bs + 8*(c ^ (h&7)));
    }
    #pragma unroll
    for(int tr=0;tr<5;tr++){
      int R = tr*16 + l15;
      int c = R*16 + kk*4 + l4;
      bf16x8 afr = *(const bf16x8*)(As + 8*(c ^ (R&7)));
      acc[tr][0] = __builtin_amdgcn_mfma_f32_16x16x32_bf16(afr, bfr[0], acc[tr][0], 0,0,0);
      acc[tr][1] = __builtin_amdgcn_mfma_f32_16x16x32_bf16(afr, bfr[1], acc[tr][1], 0,0,0);
    }
  }
  __syncthreads();

  #pragma unroll
  for(int tr=0;tr<5;tr++)
    #pragma unroll
    for(int tc=0;tc<2;tc++){
      int col = (wave*2+tc)*16 + l15;
      #pragma unroll
      for(int r=0;r<4;r++){
        int R = tr*16 + l4*4 + r;
        Cs[R*128 + col] = tanh_fast(tanh_fast(acc[tr][tc][r]));
      }
    }
  __syncthreads();

  #pragma unroll
  for(int t=0;t<4;t++){
    int oi = t*256 + tid;
    int g = oi >> 7, col = oi & 127;
    float s = 0.f;
    const float* p = Cs + g*1280 + col;
    #pragma unroll
    for(int b=0;b<10;b++) s += p[b*128];
    int nl = mb*8 + g;
    int n = nl/L_, l = nl%L_;
    na[((size_t)(n*ASP_+a)*L_ + l)*H2_ + col] = s;
  }
}

// ---------------- uHis_h: bf16 MFMA split-K (grid 4x4x25) ----------------
__global__ __launch_bounds__(256) void k_uhismm(const float* __restrict__ U,
    const float* __restrict__ W, const float* __restrict__ bias, float* __restrict__ C){
  __shared__ unsigned short As[2048];
  __shared__ unsigned short Bs[2048];
  int tid = threadIdx.x;
  int m0 = blockIdx.y*64, n0 = blockIdx.x*64;
  int kb0 = blockIdx.z*800;
  int row = tid & 63, q = tid >> 6;
  int lane = tid & 63, wave = tid >> 6;
  int l15 = lane & 15, l4 = lane >> 4;
  int wr = (wave>>1)*32, wc = (wave&1)*32;
  f32x4 acc[2][2] = {};
  for(int s=0;s<25;s++){
    int k0 = kb0 + s*32 + q*8;
    {
      const float* pa = &U[(size_t)(m0+row)*NIT_ + k0];
      float4 a0 = *(const float4*)pa, a1 = *(const float4*)(pa+4);
      bf16x8 av;
      av[0]=f2b(a0.x); av[1]=f2b(a0.y); av[2]=f2b(a0.z); av[3]=f2b(a0.w);
      av[4]=f2b(a1.x); av[5]=f2b(a1.y); av[6]=f2b(a1.z); av[7]=f2b(a1.w);
      *(bf16x8*)(As + 8*tid) = av;
      const float* pb = &W[(size_t)(n0+row)*NIT_ + k0];
      float4 b0 = *(const float4*)pb, b1 = *(const float4*)(pb+4);
      bf16x8 bv;
      bv[0]=f2b(b0.x); bv[1]=f2b(b0.y); bv[2]=f2b(b0.z); bv[3]=f2b(b0.w);
      bv[4]=f2b(b1.x); bv[5]=f2b(b1.y); bv[6]=f2b(b1.z); bv[7]=f2b(b1.w);
      *(bf16x8*)(Bs + 8*tid) = bv;
    }
    __syncthreads();
    bf16x8 afr[2], bfr[2];
    #pragma unroll
    for(int mt=0;mt<2;mt++) afr[mt] = *(const bf16x8*)(As + 8*(l4*64 + wr + mt*16 + l15));
    #pragma unroll
    for(int nt=0;nt<2;nt++) bfr[nt] = *(const bf16x8*)(Bs + 8*(l4*64 + wc + nt*16 + l15));
    #pragma unroll
    for(int mt=0;mt<2;mt++)
      #pragma unroll
      for(int nt=0;nt<2;nt++)
        acc[mt][nt] = __builtin_amdgcn_mfma_f32_16x16x32_bf16(afr[mt], bfr[nt], acc[mt][nt], 0,0,0);
    __syncthreads();
  }
  #pragma unroll
  for(int mt=0;mt<2;mt++)
    #pragma unroll
    for(int nt=0;nt<2;nt++){
      int col = n0 + wc + nt*16 + l15;
      #pragma unroll
      for(int r=0;r<4;r++){
        int rw = m0 + wr + mt*16 + l4*4 + r;
        float v = acc[mt][nt][r];
        if(blockIdx.z==0) v += bias[col];
        atomicAdd(&C[rw*H2_ + col], v);
      }
    }
}

// ---------------- xg GEMM: bf16 MFMA, in-register cast, OUTPUT bf16 ----------------
__global__ __launch_bounds__(256) void k_xgmm(const float* __restrict__ A_,
    const float* __restrict__ W, const float* __restrict__ bias,
    unsigned short* __restrict__ Cb){
  __shared__ unsigned short As[2048];
  __shared__ unsigned short Bs[2048];
  int tid = threadIdx.x;
  int n0 = blockIdx.x*64, m0 = blockIdx.y*64;
  int row = tid & 63, q = tid >> 6;
  int lane = tid & 63, wave = tid >> 6;
  int l15 = lane & 15, l4 = lane >> 4;
  int wr = (wave>>1)*32, wc = (wave&1)*32;
  f32x4 acc[2][2] = {};
  for(int s=0;s<8;s++){
    int k0 = s*32 + q*8;
    {
      const float* pa = &A_[(size_t)(m0+row)*H2_ + k0];
      float4 a0 = *(const float4*)pa, a1 = *(const float4*)(pa+4);
      bf16x8 av;
      av[0]=f2b(a0.x); av[1]=f2b(a0.y); av[2]=f2b(a0.z); av[3]=f2b(a0.w);
      av[4]=f2b(a1.x); av[5]=f2b(a1.y); av[6]=f2b(a1.z); av[7]=f2b(a1.w);
      *(bf16x8*)(As + 8*tid) = av;
      const float* pb = &W[(size_t)(n0+row)*H2_ + k0];
      float4 b0 = *(const float4*)pb, b1 = *(const float4*)(pb+4);
      bf16x8 bv;
      bv[0]=f2b(b0.x); bv[1]=f2b(b0.y); bv[2]=f2b(b0.z); bv[3]=f2b(b0.w);
      bv[4]=f2b(b1.x); bv[5]=f2b(b1.y); bv[6]=f2b(b1.z); bv[7]=f2b(b1.w);
      *(bf16x8*)(Bs + 8*tid) = bv;
    }
    __syncthreads();
    bf16x8 afr[2], bfr[2];
    #pragma unroll
    for(int mt=0;mt<2;mt++) afr[mt] = *(const bf16x8*)(As + 8*(l4*64 + wr + mt*16 + l15));
    #pragma unroll
    for(int nt=0;nt<2;nt++) bfr[nt] = *(const bf16x8*)(Bs + 8*(l4*64 + wc + nt*16 + l15));
    #pragma unroll
    for(int mt=0;mt<2;mt++)
      #pragma unroll
      for(int nt=0;nt<2;nt++)
        acc[mt][nt] = __builtin_amdgcn_mfma_f32_16x16x32_bf16(afr[mt], bfr[nt], acc[mt][nt], 0,0,0);
    __syncthreads();
  }
  #pragma unroll
  for(int mt=0;mt<2;mt++)
    #pragma unroll
    for(int nt=0;nt<2;nt++){
      int col = n0 + wc + nt*16 + l15;
      float bs = bias[col];
      #pragma unroll
      for(int r=0;r<4;r++){
        int rw = m0 + wr + mt*16 + l4*4 + r;
        Cb[(size_t)rw*G4_ + col] = f2b(acc[mt][nt][r] + bs);
      }
    }
}

// ---------------- cast out_w -> bf16 ----------------
__global__ void k_outb(const float* __restrict__ w, unsigned short* __restrict__ wb){
  int i = blockIdx.x*blockDim.x + threadIdx.x;   // 640000 threads, 8 elems each
  const float* p = w + (size_t)i*8;
  float4 a = *(const float4*)p, b = *(const float4*)(p+4);
  bf16x8 v;
  v[0]=f2b(a.x); v[1]=f2b(a.y); v[2]=f2b(a.z); v[3]=f2b(a.w);
  v[4]=f2b(b.x); v[5]=f2b(b.y); v[6]=f2b(b.z); v[7]=f2b(b.w);
  *(bf16x8*)(wb + (size_t)i*8) = v;
}

// ---------------- logits: bf16 MFMA, tile 256x32, grid 625 ----------------
__global__ __launch_bounds__(256) void k_logitsmm(const unsigned short* __restrict__ Ab,
    const unsigned short* __restrict__ Wb, const float* __restrict__ bias,
    float* __restrict__ C){
  int n0 = blockIdx.x*32;
  int tid = threadIdx.x;
  int lane = tid & 63, wave = tid >> 6;
  int l15 = lane & 15, l4 = lane >> 4;
  f32x4 acc[4][2] = {};
  #pragma unroll
  for(int kk=0;kk<8;kk++){
    int k0 = kk*32 + l4*8;
    bf16x8 bfr[2];
    #pragma unroll
    for(int nt=0;nt<2;nt++)
      bfr[nt] = *(const bf16x8*)(Wb + (size_t)(n0 + nt*16 + l15)*H2_ + k0);
    #pragma unroll
    for(int mt=0;mt<4;mt++){
      bf16x8 afr = *(const bf16x8*)(Ab + (size_t)(wave*64 + mt*16 + l15)*H2_ + k0);
      acc[mt][0] = __builtin_amdgcn_mfma_f32_16x16x32_bf16(afr, bfr[0], acc[mt][0], 0,0,0);
      acc[mt][1] = __builtin_amdgcn_mfma_f32_16x16x32_bf16(afr, bfr[1], acc[mt][1], 0,0,0);
    }
  }
  #pragma unroll
  for(int mt=0;mt<4;mt++)
    #pragma unroll
    for(int nt=0;nt<2;nt++){
      int col = n0 + nt*16 + l15;
      float bs = bias[col];
      #pragma unroll
      for(int r=0;r<4;r++){
        int row = wave*64 + mt*16 + l4*4 + r;
        C[(size_t)row*NIT_ + col] = acc[mt][nt][r] + bs;
      }
    }
}

// ---------------- generic fp32 NT GEMM (E2 only) ----------------
__global__ __launch_bounds__(256) void k_gemm(const float* __restrict__ A, const float* __restrict__ W,
    float* __restrict__ C, const float* __restrict__ bias,
    int M, int Nn, int K, int kchunk, int atomic_mode){
  __shared__ float As[64][17];
  __shared__ float Ws[64][17];
  int tid = threadIdx.x;
  int tx = tid & 15, ty = tid >> 4;
  int m0 = blockIdx.y*64, n0 = blockIdx.x*64;
  int kb0 = blockIdx.z*kchunk;
  int kend = kb0 + kchunk; if(kend > K) kend = K;
  float acc[4][4] = {};
  int lrow = tid >> 2;
  int lc4 = (tid & 3) * 4;
  for(int kb = kb0; kb < kend; kb += 16){
    {
      int gr = m0 + lrow;
      float4 v = make_float4(0,0,0,0);
      if(gr < M) v = *(const float4*)&A[(long)gr*K + kb + lc4];
      As[lrow][lc4+0]=v.x; As[lrow][lc4+1]=v.y; As[lrow][lc4+2]=v.z; As[lrow][lc4+3]=v.w;
      int gw = n0 + lrow;
      float4 u = make_float4(0,0,0,0);
      if(gw < Nn) u = *(const float4*)&W[(long)gw*K + kb + lc4];
      Ws[lrow][lc4+0]=u.x; Ws[lrow][lc4+1]=u.y; Ws[lrow][lc4+2]=u.z; Ws[lrow][lc4+3]=u.w;
    }
    __syncthreads();
    for(int k=0;k<16;k++){
      float av[4], wv[4];
      #pragma unroll
      for(int r=0;r<4;r++) av[r]=As[ty*4+r][k];
      #pragma unroll
      for(int c=0;c<4;c++) wv[c]=Ws[tx*4+c][k];
      #pragma unroll
      for(int r=0;r<4;r++)
        #pragma unroll
        for(int c=0;c<4;c++) acc[r][c] += av[r]*wv[c];
    }
    __syncthreads();
  }
  for(int r=0;r<4;r++){
    int row = m0 + ty*4 + r; if(row >= M) continue;
    for(int c=0;c<4;c++){
      int col = n0 + tx*4 + c; if(col >= Nn) continue;
      float v = acc[r][c];
      if(bias && blockIdx.z==0) v += bias[col];
      if(atomic_mode) atomicAdd(&C[(long)row*Nn+col], v);
      else C[(long)row*Nn+col] = v;
    }
  }
}

// ---------------- PI: na[n,a,l,128:256] = sum_nbr E2[nbr,l,h] + B*dh_b[h] ----------------
__global__ void k_pi(const float* __restrict__ e2, const int* __restrict__ nbr,
                     const float* __restrict__ dh_b, float* __restrict__ na){
  int n = blockIdx.x, a = blockIdx.y, h = threadIdx.x; // 128
  __shared__ int nb[KK_-1];
  if(h < KK_-1) nb[h] = nbr[(a*N_+n)*(KK_-1)+h];
  __syncthreads();
  float bias = (float)B_ * dh_b[h];
  for(int l=0;l<L_;l++){
    float s = bias;
    for(int k=0;k<KK_-1;k++) s += e2[(long)(nb[k]*L_ + l)*H_ + h];
    na[((long)(n*ASP_+a)*L_ + l)*H2_ + H_ + h] = s;
  }
}

// ---------------- x: flat reinterpret max over 4 consecutive ----------------
__global__ void k_xmax(const float* __restrict__ na, float* __restrict__ x){
  int i = blockIdx.x*blockDim.x + threadIdx.x;
  if(i >= N_*L_*H2_) return;
  int n = i / (L_*H2_);
  int j = i % (L_*H2_);
  const float* p = &na[(long)n*ASP_*L_*H2_ + 4*j];
  x[i] = fmaxf(fmaxf(p[0],p[1]), fmaxf(p[2],p[3]));
}

// ---------------- fused LSTM layer (r15 structure, proven 122 us/layer) ----------------
// 16 blocks x 1024 thr (16 waves). Transposed MFMA; gate-tile 0 LDS-cached (128KB),
// tiles 1..3 streamed from L2 (384KB/step); xg bf16; h dbuf 16KB; 1 barrier/step.
__global__ __launch_bounds__(1024) void k_lstm_layer(
    const unsigned short* __restrict__ Whb,   // [1024][256] bf16 permuted (col=jj*4+g)
    const unsigned short* __restrict__ xgb,   // [256][20][1024] bf16 ih products
    float* __restrict__ Y){                   // [256][20][256] fp32 h sequence
  __shared__ unsigned short wc[65536];        // 128 KB: 16 waves x 8KB (gate-tile 0 each)
  __shared__ unsigned short hs[2][16*H2_];    // 2 x 8 KB, chunk ch=s*32+k/8, swz ^(s&7)
  int tid = threadIdx.x;
  int n0 = blockIdx.x * 16;
  int lane = tid & 63, wave = tid >> 6;       // wave 0..15, owns gate tiles wave*4..+3
  int l15 = lane & 15, l4 = lane >> 4;
  int n = n0 + l15;
  float creg[4] = {0.f,0.f,0.f,0.f};
  {
    int ct0 = wave*4;
    #pragma unroll
    for(int it=0; it<8; it++){
      int c = it*64 + lane;
      int row = c >> 5;
      bf16x8 w8 = *(const bf16x8*)(Whb + (size_t)(ct0*16+row)*H2_ + (c&31)*8);
      *(bf16x8*)(wc + 8*((wave<<9) + (c ^ (row&7)))) = w8;
    }
  }
  const unsigned short* wptr[3];
  #pragma unroll
  for(int i=0;i<3;i++) wptr[i] = Whb + (size_t)((wave*4+1+i)*16 + l15)*H2_ + l4*8;
  const unsigned short* wc0 = wc + (wave<<12);
  __syncthreads();
  for(int t=0; t<L_; t++){
    bf16x4 xgv[4];
    #pragma unroll
    for(int i=0;i<4;i++){
      int jj = wave*16 + i*4 + l4;
      xgv[i] = *(const bf16x4*)(xgb + ((size_t)n*L_ + t)*G4_ + jj*4);
    }
    f32x4 acc[4] = {};
    if(t > 0){
      const unsigned short* hbuf = hs[(t+1)&1];
      bf16x8 hfr[8];
      #pragma unroll
      for(int kk=0; kk<8; kk++){
        int ch = l15*32 + kk*4 + l4;
        hfr[kk] = *(const bf16x8*)(hbuf + 8*(ch ^ (l15&7)));
      }
      #pragma unroll
      for(int kk=0; kk<8; kk++){
        bf16x8 wfr[4];
        wfr[0] = *(const bf16x8*)(wc0 + 8*((l15*32 + kk*4 + l4) ^ (l15&7)));
        #pragma unroll
        for(int i=0;i<3;i++) wfr[1+i] = *(const bf16x8*)(wptr[i] + kk*32);
        #pragma unroll
        for(int i=0;i<4;i++)
          acc[i] = __builtin_amdgcn_mfma_f32_16x16x32_bf16(wfr[i], hfr[kk], acc[i], 0,0,0);
      }
    }
    unsigned short* hout = hs[t&1];
    #pragma unroll
    for(int i=0;i<4;i++){
      int jj = wave*16 + i*4 + l4;
      float gi = acc[i][0] + b2f((unsigned short)xgv[i][0]);
      float gf = acc[i][1] + b2f((unsigned short)xgv[i][1]);
      float gg = acc[i][2] + b2f((unsigned short)xgv[i][2]);
      float go = acc[i][3] + b2f((unsigned short)xgv[i][3]);
      float cnew = sigf_fast(gf)*creg[i] + sigf_fast(gi)*tanh_fast(gg);
      creg[i] = cnew;
      float hnew = sigf_fast(go)*tanh_fast(cnew);
      Y[((size_t)n*L_ + t)*H2_ + jj] = hnew;
      int ch = l15*32 + (jj>>3);
      *(unsigned short*)((char*)hout + 16*(ch ^ (l15&7)) + (jj&7)*2) = f2b(hnew);
    }
    __syncthreads();
  }
}

// ---------------- fused h_agg + gate (uhismm must precede) ----------------
__global__ void k_hagg_gate(const float* __restrict__ y1, const float* __restrict__ uhish,
                            const float* __restrict__ g1w, const float* __restrict__ g1b,
                            const float* __restrict__ g2w, const float* __restrict__ g2b,
                            float* __restrict__ hagg, unsigned short* __restrict__ haggb,
                            float* __restrict__ gate){
  int n = blockIdx.x; int jj = threadIdx.x;   // 256
  float s=0.f;
  for(int t=0;t<L_;t++) s += y1[((long)n*L_+t)*H2_ + jj];
  float v = tanhf(s);
  hagg[n*H2_+jj] = v;
  haggb[n*H2_+jj] = f2b(v);
  __shared__ float red[256];
  red[jj] = uhish[n*H2_+jj]*g1w[jj] + v*g2w[jj];
  __syncthreads();
  for(int o=128;o>0;o>>=1){ if(jj<o) red[jj]+=red[jj+o]; __syncthreads(); }
  if(jj==0) gate[n] = 1.f/(1.f+expf(-(red[0]+g1b[0]+g2b[0])));
}

// ---------------- fused softmax stats + final blend (row stays in L2) ----------------
__global__ __launch_bounds__(512) void k_softmax_out(const float* __restrict__ logits,
    const float* __restrict__ gate, const float* __restrict__ uHis, float* __restrict__ out){
  int n = blockIdx.x; int t = threadIdx.x;    // 512
  const float* row = &logits[(long)n*NIT_];
  float m = -3.4e38f;
  for(int i=t;i<NIT_;i+=512) m = fmaxf(m, row[i]);
  __shared__ float red[512];
  __shared__ float mm, ss;
  red[t]=m; __syncthreads();
  for(int o=256;o>0;o>>=1){ if(t<o) red[t]=fmaxf(red[t],red[t+o]); __syncthreads(); }
  if(t==0) mm = red[0];
  __syncthreads();
  float s=0.f;
  for(int i=t;i<NIT_;i+=512) s += __expf(row[i]-mm);
  __syncthreads();
  red[t]=s; __syncthreads();
  for(int o=256;o>0;o>>=1){ if(t<o) red[t]+=red[t+o]; __syncthreads(); }
  if(t==0) ss = red[0];
  __syncthreads();
  float g = gate[n];
  float* orow = out + (long)n*NIT_;
  const float* urow = uHis + (long)n*NIT_;
  for(int i=t;i<NIT_;i+=512){
    float p = __expf(row[i]-mm)/ss;
    orow[i] = g*p + (1.f-g)*urow[i];
  }
}

extern "C" void kernel_launch(void* const* d_in, const int* in_sizes, int n_in,
                              void* d_out, int out_size, void* d_ws, size_t ws_size,
                              hipStream_t stream) {
  const int*   seq     = (const int*)  d_in[0];
  const float* uHis    = (const float*)d_in[1];
  const float* itemEmb = (const float*)d_in[2];
  const float* fc1_w   = (const float*)d_in[3];
  const float* fc1_b   = (const float*)d_in[4];
  const float* aspProju= (const float*)d_in[5];
  const float* aspProji= (const float*)d_in[6];
  const float* dh_w    = (const float*)d_in[7];
  const float* dh_b    = (const float*)d_in[8];
  const float* wih0    = (const float*)d_in[9];
  const float* whh0    = (const float*)d_in[10];
  const float* bih0    = (const float*)d_in[11];
  const float* bhh0    = (const float*)d_in[12];
  const float* wih1    = (const float*)d_in[13];
  const float* whh1    = (const float*)d_in[14];
  const float* bih1    = (const float*)d_in[15];
  const float* bhh1    = (const float*)d_in[16];
  const float* out_w   = (const float*)d_in[17];
  const float* out_b   = (const float*)d_in[18];
  const float* his_w   = (const float*)d_in[19];
  const float* his_b   = (const float*)d_in[20];
  const float* g1_w    = (const float*)d_in[21];
  const float* g1_b    = (const float*)d_in[22];
  const float* g2_w    = (const float*)d_in[23];
  const float* g2_b    = (const float*)d_in[24];

  float* ws = (float*)d_ws;
  float* embs = ws + 0;            // 6,553,600   (reused as logits later)
  float* cub  = ws + 6553600;      // 6,553,600   (ebh bf16 shadow; reused as xgb bf16 later)
  float* na   = ws + 13107200;     // 5,242,880   (reused as outwb bf16 after xmax)
  float* x    = ws + 18350080;     // 1,310,720   (reused as haggb after xg0)
  float* y0   = ws + 19660800;     // 1,310,720
  float* y1   = ws + 20971520;     // 1,310,720
  float* eb   = ws + 22282240;     //   655,360
  float* e2   = ws + 22937600;     //   655,360
  float* ua   = ws + 23855104;     //   131,072
  float* projT= ws + 23986176;     //    65,536  (holds projb bf16)
  float* wp0  = ws + 24051712;     //   262,144
  float* whp0 = ws + 24313856;     //   262,144  (bf16 permuted whh0)
  float* wp1  = ws + 24576000;     //   262,144
  float* whp1 = ws + 24838144;     //   262,144  (bf16 permuted whh1)
  float* bp0  = ws + 25100288;     //     1,024
  float* bp1  = ws + 25101312;     //     1,024
  float* uemb = ws + 25167872;     //       256
  float* sqb  = ws + 25168128;     //     1,024
  int*   nbr  = (int*)(ws + 25169152); // 15,360 ints
  float* uhish= ws + 25184512;     //    65,536
  float* hagg = ws + 25250048;     //    65,536
  float* gateb =ws + 25316096;     //       256
  float* logits = embs;            // reuse
  unsigned short* ebh   = (unsigned short*)cub;   // bf16 shadow (inside cub slot)
  unsigned short* xgb   = (unsigned short*)cub;   // bf16 xg (ebh dead after k_uimm)
  unsigned short* projb = (unsigned short*)projT; // bf16 (inside projT slot)
  unsigned short* outwb = (unsigned short*)na;    // bf16 out_w (na dead after xmax)
  unsigned short* haggb = (unsigned short*)x;     // bf16 hagg (x dead after xg0)
  unsigned short* whb0  = (unsigned short*)whp0;  // bf16 permuted whh0
  unsigned short* whb1  = (unsigned short*)whp1;  // bf16 permuted whh1

  // 1. embedding gather (fp32 + bf16 shadow)
  k_gather<<<NLB_, D_, 0, stream>>>(seq, itemEmb, embs, ebh);
  // 2. fc1 -> u_embs
  k_fc1<<<N_, 256, 0, stream>>>(embs, fc1_w, fc1_b, uemb);
  // 3. fused uA + sq
  k_uasq<<<ASP_*N_, 128, 0, stream>>>(uemb, aspProju, ua, sqb);
  // 4. fused dist + top-k
  k_disttopk<<<dim3(N_,ASP_), 256, 0, stream>>>(ua, sqb, nbr);
  // 5. EB = sum_b embs
  k_eb<<<NL_, D_, 0, stream>>>(embs, eb);
  // 6. E2 = EB @ dh_w^T
  k_gemm<<<dim3(2, 80, 1), 256, 0, stream>>>(eb, dh_w, e2, nullptr, NL_, H_, D_, D_, 0);
  // 7. fused prep (LSTM permutes + biases + projb)
  k_prep<<<4360, 256, 0, stream>>>(wih0, whh0, wih1, whh1, bih0, bhh0, bih1, bhh1,
                                   aspProji, wp0, whb0, wp1, whb1, bp0, bp1, projb);
  // 8. fused UI stage
  k_uimm<<<dim3(NL_/8, ASP_), 256, 0, stream>>>(ebh, projb, na);
  // 9. PI (neighbor sums)
  k_pi<<<dim3(N_,ASP_), H_, 0, stream>>>(e2, nbr, dh_b, na);
  // 10. x = flat max-4
  k_xmax<<<(N_*L_*H2_+255)/256, 256, 0, stream>>>(na, x);
  // 11. cast out_w -> bf16 (into dead na region)
  k_outb<<<2500, 256, 0, stream>>>(out_w, outwb);
  // 12. xg0 = x @ wp0^T + bp0 : bf16 MFMA, bf16 output
  k_xgmm<<<dim3(16,80), 256, 0, stream>>>(x, wp0, bp0, xgb);
  // 13. LSTM layer 0 (r15 structure)
  k_lstm_layer<<<16, 1024, 0, stream>>>(whb0, xgb, y0);
  // 14. xg1 = y0 @ wp1^T + bp1
  k_xgmm<<<dim3(16,80), 256, 0, stream>>>(y0, wp1, bp1, xgb);
  // 15. LSTM layer 1
  k_lstm_layer<<<16, 1024, 0, stream>>>(whb1, xgb, y1);
  // 16. uHis_h = uHis @ his_w^T + his_b : bf16 MFMA split-K
  hipMemsetAsync(uhish, 0, N_*H2_*sizeof(float), stream);
  k_uhismm<<<dim3(4,4,25), 256, 0, stream>>>(uHis, his_w, his_b, uhish);
  // 17. fused h_agg + gate
  k_hagg_gate<<<N_, 256, 0, stream>>>(y1, uhish, g1_w, g1_b, g2_w, g2_b, hagg, haggb, gateb);
  // 18. logits = h_agg @ out_w^T + out_b
  k_logitsmm<<<625, 256, 0, stream>>>(haggb, outwb, out_b, logits);
  // 19. fused softmax + final blend
  k_softmax_out<<<N_, 512, 0, stream>>>(logits, gateb, uHis, (float*)d_out);
}

// Round 18
// 500.116 us; speedup vs baseline: 1.0445x; 1.0445x over previous
//
#include <hip/hip_runtime.h>
#include <math.h>

#define N_ 256
#define L_ 20
#define B_ 10
#define D_ 128
#define H_ 128
#define ASP_ 4
#define KK_ 16
#define NIT_ 20000
#define H2_ 256
#define G4_ 1024
#define LBD_ 25600
#define NL_ 5120
#define NLB_ 51200

typedef __attribute__((ext_vector_type(8))) short bf16x8;
typedef __attribute__((ext_vector_type(4))) short bf16x4;
typedef __attribute__((ext_vector_type(4))) float f32x4;

__device__ __forceinline__ float sigf_fast(float x){
  return __builtin_amdgcn_rcpf(1.0f + __expf(-x));
}
__device__ __forceinline__ float tanh_fast(float x){
  return 1.0f - 2.0f*__builtin_amdgcn_rcpf(__expf(2.0f*x) + 1.0f);
}
__device__ __forceinline__ unsigned short f2b(float f){
  unsigned int u = __float_as_uint(f);
  unsigned int r = (u + 0x7FFFu + ((u>>16)&1u)) >> 16;   // RNE
  return (unsigned short)r;
}
__device__ __forceinline__ float b2f(unsigned short b){
  return __uint_as_float(((unsigned int)b) << 16);
}

// ---------------- fused gather + EB: embs/ebh rows + eb[n,l,:] = sum_b ----------------
__global__ void k_gather2(const int* __restrict__ seq, const float* __restrict__ itemEmb,
                          float* __restrict__ embs, unsigned short* __restrict__ ebh,
                          float* __restrict__ eb){
  int nl = blockIdx.x;           // 0..5119
  int d = threadIdx.x;           // 0..127
  float s = 0.f;
  #pragma unroll
  for(int b=0;b<B_;b++){
    int idx = seq[nl*B_ + b];
    float v = itemEmb[(size_t)idx*D_ + d];
    embs[(size_t)(nl*B_+b)*D_ + d] = v;
    ebh[(size_t)(nl*B_+b)*D_ + d] = f2b(v);
    s += v;
  }
  eb[(size_t)nl*D_ + d] = s;
}

// ---------------- fc1: u[n] = dot(embs[n,:], fc1_w) + fc1_b ----------------
__global__ void k_fc1(const float* __restrict__ embs, const float* __restrict__ w,
                      const float* __restrict__ b, float* __restrict__ u){
  int n = blockIdx.x; int t = threadIdx.x;
  float s = 0.f;
  for (int i = t; i < LBD_; i += 256) s += embs[n*LBD_+i]*w[i];
  __shared__ float red[256];
  red[t]=s; __syncthreads();
  for (int o=128;o>0;o>>=1){ if(t<o) red[t]+=red[t+o]; __syncthreads(); }
  if(t==0) u[n]=red[0]+b[0];
}

// ---------------- fused uA + sq (libm tanh: kNN path stays bit-stable) ----------------
__global__ void k_uasq(const float* __restrict__ u, const float* __restrict__ proju,
                       float* __restrict__ ua, float* __restrict__ sq){
  int an = blockIdx.x;           // a*N_+n
  int h = threadIdx.x;           // 128
  int a = an / N_, n = an % N_;
  float v = tanhf(tanhf(u[n]*proju[a*H_+h]));
  ua[an*H_ + h] = v;
  __shared__ float red[128];
  red[h] = v*v; __syncthreads();
  for(int o=64;o>0;o>>=1){ if(h<o) red[h]+=red[h+o]; __syncthreads(); }
  if(h==0) sq[an]=red[0];
}

// ---------------- fused dist + top-16 (bit-identical selection) ----------------
__global__ __launch_bounds__(256) void k_disttopk(const float* __restrict__ ua,
    const float* __restrict__ sq, int* __restrict__ nbr){
  int n = blockIdx.x, a = blockIdx.y, m = threadIdx.x;  // 256 threads
  __shared__ float un[H_];
  __shared__ float row[N_];
  if(m < H_) un[m] = ua[(a*N_+n)*H_ + m];
  __syncthreads();
  const float* um = &ua[(a*N_+m)*H_];
  float dot=0.f;
  for(int h=0;h<H_;h++) dot += un[h]*um[h];
  float dval = sq[a*N_+n] + sq[a*N_+m] - 2.f*dot;
  if(m==n) dval = -1.0f;
  row[m] = dval;
  __syncthreads();
  if(m < 64){
    int lane = m;
    int wid = a*N_+n;
    float v[4]; int idx[4];
    #pragma unroll
    for(int j=0;j<4;j++){ int mm = lane*4 + j; v[j] = row[mm]; idx[j] = mm; }
    for(int k=0;k<KK_;k++){
      float bv = v[0]; int bi = idx[0];
      #pragma unroll
      for(int j=1;j<4;j++)
        if(v[j] < bv || (v[j]==bv && idx[j] < bi)){ bv=v[j]; bi=idx[j]; }
      float rv = bv; int ri = bi;
      #pragma unroll
      for(int o=32;o>0;o>>=1){
        float ov = __shfl_xor(rv, o, 64);
        int   oi = __shfl_xor(ri, o, 64);
        if(ov < rv || (ov==rv && oi < ri)){ rv=ov; ri=oi; }
      }
      if((ri>>2) == lane){ v[ri&3] = 3.4e38f; idx[ri&3] = 0x7fffffff; }
      if(k>0 && lane==0) nbr[wid*(KK_-1)+(k-1)] = ri;
    }
  }
}

// ---------------- fused prep: LSTM weight permutes + biases + projb ----------------
__global__ void k_prep(const float* __restrict__ wih0, const float* __restrict__ whh0,
                       const float* __restrict__ wih1, const float* __restrict__ whh1,
                       const float* __restrict__ bih0, const float* __restrict__ bhh0,
                       const float* __restrict__ bih1, const float* __restrict__ bhh1,
                       const float* __restrict__ proji,
                       float* __restrict__ wp0, unsigned short* __restrict__ whb0,
                       float* __restrict__ wp1, unsigned short* __restrict__ whb1,
                       float* __restrict__ bp0, float* __restrict__ bp1,
                       unsigned short* __restrict__ projb){
  int i = blockIdx.x*blockDim.x + threadIdx.x;
  if(i < 262144){
    int k=i%H2_, j=i/H2_, g=j/H2_, jj=j%H2_;
    wp0[(jj*4+g)*H2_+k] = wih0[i];
  } else if(i < 524288){
    int e=i-262144; int k=e%H2_, j=e/H2_, g=j/H2_, jj=j%H2_;
    whb0[(jj*4+g)*H2_+k] = f2b(whh0[e]);
  } else if(i < 786432){
    int e=i-524288; int k=e%H2_, j=e/H2_, g=j/H2_, jj=j%H2_;
    wp1[(jj*4+g)*H2_+k] = wih1[e];
  } else if(i < 1048576){
    int e=i-786432; int k=e%H2_, j=e/H2_, g=j/H2_, jj=j%H2_;
    whb1[(jj*4+g)*H2_+k] = f2b(whh1[e]);
  } else if(i < 1114112){
    int e=i-1048576; int h=e%H_, d=(e/H_)%D_, aa=e/(D_*H_);
    projb[(aa*H_+h)*D_+d] = f2b(proji[e]);
  } else if(i < 1115136){
    int j=i-1114112; int g=j/H2_, jj=j%H2_;
    bp0[jj*4+g] = bih0[j] + bhh0[j];
  } else if(i < 1116160){
    int j=i-1115136; int g=j/H2_, jj=j%H2_;
    bp1[jj*4+g] = bih1[j] + bhh1[j];
  }
}

// ---------------- fused UI stage: MFMA bf16 GEMM + tanh^2 + sum_b -> na[.., 0:128] ----------------
__global__ __launch_bounds__(256) void k_uimm(const unsigned short* __restrict__ ebh,
                                              const unsigned short* __restrict__ projb,
                                              float* __restrict__ na){
  __shared__ char smem[53248];
  unsigned short* As = (unsigned short*)smem;            // 80x128 bf16, swizzled 16B chunks
  unsigned short* Bs = (unsigned short*)(smem + 20480);  // 128x128 bf16, swizzled
  float*          Cs = (float*)smem;                     // 80x128 f32 (aliases As+Bs later)

  int mb = blockIdx.x;   // 0..639
  int a  = blockIdx.y;   // 0..3
  int tid = threadIdx.x;

  const unsigned short* asrc = ebh + (size_t)mb*10240;
  #pragma unroll
  for(int t=0;t<5;t++){
    int c = tid + t*256;
    int row = c >> 4;
    *(bf16x8*)(As + 8*(c ^ (row&7))) = *(const bf16x8*)(asrc + 8*c);
  }
  const unsigned short* bsrc = projb + a*16384;
  #pragma unroll
  for(int t=0;t<8;t++){
    int c = tid + t*256;
    int row = c >> 4;
    *(bf16x8*)(Bs + 8*(c ^ (row&7))) = *(const bf16x8*)(bsrc + 8*c);
  }
  __syncthreads();

  int lane = tid & 63, wave = tid >> 6;
  int l15 = lane & 15, l4 = lane >> 4;
  f32x4 acc[5][2] = {};
  #pragma unroll
  for(int kk=0;kk<4;kk++){
    bf16x8 bfr[2];
    #pragma unroll
    for(int tc=0;tc<2;tc++){
      int h = (wave*2+tc)*16 + l15;
      int c = h*16 + kk*4 + l4;
      bfr[tc] = *(const bf16x8*)(Bs + 8*(c ^ (h&7)));
    }
    #pragma unroll
    for(int tr=0;tr<5;tr++){
      int R = tr*16 + l15;
      int c = R*16 + kk*4 + l4;
      bf16x8 afr = *(const bf16x8*)(As + 8*(c ^ (R&7)));
      acc[tr][0] = __builtin_amdgcn_mfma_f32_16x16x32_bf16(afr, bfr[0], acc[tr][0], 0,0,0);
      acc[tr][1] = __builtin_amdgcn_mfma_f32_16x16x32_bf16(afr, bfr[1], acc[tr][1], 0,0,0);
    }
  }
  __syncthreads();

  #pragma unroll
  for(int tr=0;tr<5;tr++)
    #pragma unroll
    for(int tc=0;tc<2;tc++){
      int col = (wave*2+tc)*16 + l15;
      #pragma unroll
      for(int r=0;r<4;r++){
        int R = tr*16 + l4*4 + r;
        Cs[R*128 + col] = tanh_fast(tanh_fast(acc[tr][tc][r]));
      }
    }
  __syncthreads();

  #pragma unroll
  for(int t=0;t<4;t++){
    int oi = t*256 + tid;
    int g = oi >> 7, col = oi & 127;
    float s = 0.f;
    const float* p = Cs + g*1280 + col;
    #pragma unroll
    for(int b=0;b<10;b++) s += p[b*128];
    int nl = mb*8 + g;
    int n = nl/L_, l = nl%L_;
    na[((size_t)(n*ASP_+a)*L_ + l)*H2_ + col] = s;
  }
}

// ---------------- uHis_h: bf16 MFMA split-K (grid 4x4x25) ----------------
__global__ __launch_bounds__(256) void k_uhismm(const float* __restrict__ U,
    const float* __restrict__ W, const float* __restrict__ bias, float* __restrict__ C){
  __shared__ unsigned short As[2048];
  __shared__ unsigned short Bs[2048];
  int tid = threadIdx.x;
  int m0 = blockIdx.y*64, n0 = blockIdx.x*64;
  int kb0 = blockIdx.z*800;
  int row = tid & 63, q = tid >> 6;
  int lane = tid & 63, wave = tid >> 6;
  int l15 = lane & 15, l4 = lane >> 4;
  int wr = (wave>>1)*32, wc = (wave&1)*32;
  f32x4 acc[2][2] = {};
  for(int s=0;s<25;s++){
    int k0 = kb0 + s*32 + q*8;
    {
      const float* pa = &U[(size_t)(m0+row)*NIT_ + k0];
      float4 a0 = *(const float4*)pa, a1 = *(const float4*)(pa+4);
      bf16x8 av;
      av[0]=f2b(a0.x); av[1]=f2b(a0.y); av[2]=f2b(a0.z); av[3]=f2b(a0.w);
      av[4]=f2b(a1.x); av[5]=f2b(a1.y); av[6]=f2b(a1.z); av[7]=f2b(a1.w);
      *(bf16x8*)(As + 8*tid) = av;
      const float* pb = &W[(size_t)(n0+row)*NIT_ + k0];
      float4 b0 = *(const float4*)pb, b1 = *(const float4*)(pb+4);
      bf16x8 bv;
      bv[0]=f2b(b0.x); bv[1]=f2b(b0.y); bv[2]=f2b(b0.z); bv[3]=f2b(b0.w);
      bv[4]=f2b(b1.x); bv[5]=f2b(b1.y); bv[6]=f2b(b1.z); bv[7]=f2b(b1.w);
      *(bf16x8*)(Bs + 8*tid) = bv;
    }
    __syncthreads();
    bf16x8 afr[2], bfr[2];
    #pragma unroll
    for(int mt=0;mt<2;mt++) afr[mt] = *(const bf16x8*)(As + 8*(l4*64 + wr + mt*16 + l15));
    #pragma unroll
    for(int nt=0;nt<2;nt++) bfr[nt] = *(const bf16x8*)(Bs + 8*(l4*64 + wc + nt*16 + l15));
    #pragma unroll
    for(int mt=0;mt<2;mt++)
      #pragma unroll
      for(int nt=0;nt<2;nt++)
        acc[mt][nt] = __builtin_amdgcn_mfma_f32_16x16x32_bf16(afr[mt], bfr[nt], acc[mt][nt], 0,0,0);
    __syncthreads();
  }
  #pragma unroll
  for(int mt=0;mt<2;mt++)
    #pragma unroll
    for(int nt=0;nt<2;nt++){
      int col = n0 + wc + nt*16 + l15;
      #pragma unroll
      for(int r=0;r<4;r++){
        int rw = m0 + wr + mt*16 + l4*4 + r;
        float v = acc[mt][nt][r];
        if(blockIdx.z==0) v += bias[col];
        atomicAdd(&C[rw*H2_ + col], v);
      }
    }
}

// ---------------- xg GEMM: bf16 MFMA, in-register cast, OUTPUT bf16 ----------------
__global__ __launch_bounds__(256) void k_xgmm(const float* __restrict__ A_,
    const float* __restrict__ W, const float* __restrict__ bias,
    unsigned short* __restrict__ Cb){
  __shared__ unsigned short As[2048];
  __shared__ unsigned short Bs[2048];
  int tid = threadIdx.x;
  int n0 = blockIdx.x*64, m0 = blockIdx.y*64;
  int row = tid & 63, q = tid >> 6;
  int lane = tid & 63, wave = tid >> 6;
  int l15 = lane & 15, l4 = lane >> 4;
  int wr = (wave>>1)*32, wc = (wave&1)*32;
  f32x4 acc[2][2] = {};
  for(int s=0;s<8;s++){
    int k0 = s*32 + q*8;
    {
      const float* pa = &A_[(size_t)(m0+row)*H2_ + k0];
      float4 a0 = *(const float4*)pa, a1 = *(const float4*)(pa+4);
      bf16x8 av;
      av[0]=f2b(a0.x); av[1]=f2b(a0.y); av[2]=f2b(a0.z); av[3]=f2b(a0.w);
      av[4]=f2b(a1.x); av[5]=f2b(a1.y); av[6]=f2b(a1.z); av[7]=f2b(a1.w);
      *(bf16x8*)(As + 8*tid) = av;
      const float* pb = &W[(size_t)(n0+row)*H2_ + k0];
      float4 b0 = *(const float4*)pb, b1 = *(const float4*)(pb+4);
      bf16x8 bv;
      bv[0]=f2b(b0.x); bv[1]=f2b(b0.y); bv[2]=f2b(b0.z); bv[3]=f2b(b0.w);
      bv[4]=f2b(b1.x); bv[5]=f2b(b1.y); bv[6]=f2b(b1.z); bv[7]=f2b(b1.w);
      *(bf16x8*)(Bs + 8*tid) = bv;
    }
    __syncthreads();
    bf16x8 afr[2], bfr[2];
    #pragma unroll
    for(int mt=0;mt<2;mt++) afr[mt] = *(const bf16x8*)(As + 8*(l4*64 + wr + mt*16 + l15));
    #pragma unroll
    for(int nt=0;nt<2;nt++) bfr[nt] = *(const bf16x8*)(Bs + 8*(l4*64 + wc + nt*16 + l15));
    #pragma unroll
    for(int mt=0;mt<2;mt++)
      #pragma unroll
      for(int nt=0;nt<2;nt++)
        acc[mt][nt] = __builtin_amdgcn_mfma_f32_16x16x32_bf16(afr[mt], bfr[nt], acc[mt][nt], 0,0,0);
    __syncthreads();
  }
  #pragma unroll
  for(int mt=0;mt<2;mt++)
    #pragma unroll
    for(int nt=0;nt<2;nt++){
      int col = n0 + wc + nt*16 + l15;
      float bs = bias[col];
      #pragma unroll
      for(int r=0;r<4;r++){
        int rw = m0 + wr + mt*16 + l4*4 + r;
        Cb[(size_t)rw*G4_ + col] = f2b(acc[mt][nt][r] + bs);
      }
    }
}

// ---------------- logits: bf16 MFMA, fp32 out_w cast in-register (k_outb removed) ----------------
__global__ __launch_bounds__(256) void k_logitsmm(const unsigned short* __restrict__ Ab,
    const float* __restrict__ Wf, const float* __restrict__ bias,
    float* __restrict__ C){
  int n0 = blockIdx.x*32;
  int tid = threadIdx.x;
  int lane = tid & 63, wave = tid >> 6;
  int l15 = lane & 15, l4 = lane >> 4;
  f32x4 acc[4][2] = {};
  #pragma unroll
  for(int kk=0;kk<8;kk++){
    int k0 = kk*32 + l4*8;
    bf16x8 bfr[2];
    #pragma unroll
    for(int nt=0;nt<2;nt++){
      const float* pb = &Wf[(size_t)(n0 + nt*16 + l15)*H2_ + k0];
      float4 b0 = *(const float4*)pb, b1 = *(const float4*)(pb+4);
      bf16x8 bv;
      bv[0]=f2b(b0.x); bv[1]=f2b(b0.y); bv[2]=f2b(b0.z); bv[3]=f2b(b0.w);
      bv[4]=f2b(b1.x); bv[5]=f2b(b1.y); bv[6]=f2b(b1.z); bv[7]=f2b(b1.w);
      bfr[nt] = bv;
    }
    #pragma unroll
    for(int mt=0;mt<4;mt++){
      bf16x8 afr = *(const bf16x8*)(Ab + (size_t)(wave*64 + mt*16 + l15)*H2_ + k0);
      acc[mt][0] = __builtin_amdgcn_mfma_f32_16x16x32_bf16(afr, bfr[0], acc[mt][0], 0,0,0);
      acc[mt][1] = __builtin_amdgcn_mfma_f32_16x16x32_bf16(afr, bfr[1], acc[mt][1], 0,0,0);
    }
  }
  #pragma unroll
  for(int mt=0;mt<4;mt++)
    #pragma unroll
    for(int nt=0;nt<2;nt++){
      int col = n0 + nt*16 + l15;
      float bs = bias[col];
      #pragma unroll
      for(int r=0;r<4;r++){
        int row = wave*64 + mt*16 + l4*4 + r;
        C[(size_t)row*NIT_ + col] = acc[mt][nt][r] + bs;
      }
    }
}

// ---------------- generic fp32 NT GEMM (E2 only) ----------------
__global__ __launch_bounds__(256) void k_gemm(const float* __restrict__ A, const float* __restrict__ W,
    float* __restrict__ C, const float* __restrict__ bias,
    int M, int Nn, int K, int kchunk, int atomic_mode){
  __shared__ float As[64][17];
  __shared__ float Ws[64][17];
  int tid = threadIdx.x;
  int tx = tid & 15, ty = tid >> 4;
  int m0 = blockIdx.y*64, n0 = blockIdx.x*64;
  int kb0 = blockIdx.z*kchunk;
  int kend = kb0 + kchunk; if(kend > K) kend = K;
  float acc[4][4] = {};
  int lrow = tid >> 2;
  int lc4 = (tid & 3) * 4;
  for(int kb = kb0; kb < kend; kb += 16){
    {
      int gr = m0 + lrow;
      float4 v = make_float4(0,0,0,0);
      if(gr < M) v = *(const float4*)&A[(long)gr*K + kb + lc4];
      As[lrow][lc4+0]=v.x; As[lrow][lc4+1]=v.y; As[lrow][lc4+2]=v.z; As[lrow][lc4+3]=v.w;
      int gw = n0 + lrow;
      float4 u = make_float4(0,0,0,0);
      if(gw < Nn) u = *(const float4*)&W[(long)gw*K + kb + lc4];
      Ws[lrow][lc4+0]=u.x; Ws[lrow][lc4+1]=u.y; Ws[lrow][lc4+2]=u.z; Ws[lrow][lc4+3]=u.w;
    }
    __syncthreads();
    for(int k=0;k<16;k++){
      float av[4], wv[4];
      #pragma unroll
      for(int r=0;r<4;r++) av[r]=As[ty*4+r][k];
      #pragma unroll
      for(int c=0;c<4;c++) wv[c]=Ws[tx*4+c][k];
      #pragma unroll
      for(int r=0;r<4;r++)
        #pragma unroll
        for(int c=0;c<4;c++) acc[r][c] += av[r]*wv[c];
    }
    __syncthreads();
  }
  for(int r=0;r<4;r++){
    int row = m0 + ty*4 + r; if(row >= M) continue;
    for(int c=0;c<4;c++){
      int col = n0 + tx*4 + c; if(col >= Nn) continue;
      float v = acc[r][c];
      if(bias && blockIdx.z==0) v += bias[col];
      if(atomic_mode) atomicAdd(&C[(long)row*Nn+col], v);
      else C[(long)row*Nn+col] = v;
    }
  }
}

// ---------------- PI: na[n,a,l,128:256] = sum_nbr E2[nbr,l,h] + B*dh_b[h] ----------------
__global__ void k_pi(const float* __restrict__ e2, const int* __restrict__ nbr,
                     const float* __restrict__ dh_b, float* __restrict__ na){
  int n = blockIdx.x, a = blockIdx.y, h = threadIdx.x; // 128
  __shared__ int nb[KK_-1];
  if(h < KK_-1) nb[h] = nbr[(a*N_+n)*(KK_-1)+h];
  __syncthreads();
  float bias = (float)B_ * dh_b[h];
  for(int l=0;l<L_;l++){
    float s = bias;
    for(int k=0;k<KK_-1;k++) s += e2[(long)(nb[k]*L_ + l)*H_ + h];
    na[((long)(n*ASP_+a)*L_ + l)*H2_ + H_ + h] = s;
  }
}

// ---------------- x: flat reinterpret max over 4 consecutive ----------------
__global__ void k_xmax(const float* __restrict__ na, float* __restrict__ x){
  int i = blockIdx.x*blockDim.x + threadIdx.x;
  if(i >= N_*L_*H2_) return;
  int n = i / (L_*H2_);
  int j = i % (L_*H2_);
  const float* p = &na[(long)n*ASP_*L_*H2_ + 4*j];
  x[i] = fmaxf(fmaxf(p[0],p[1]), fmaxf(p[2],p[3]));
}

// ---------------- fused LSTM layer (r15 structure, proven 122 us/layer) ----------------
__global__ __launch_bounds__(1024) void k_lstm_layer(
    const unsigned short* __restrict__ Whb,   // [1024][256] bf16 permuted (col=jj*4+g)
    const unsigned short* __restrict__ xgb,   // [256][20][1024] bf16 ih products
    float* __restrict__ Y){                   // [256][20][256] fp32 h sequence
  __shared__ unsigned short wc[65536];        // 128 KB: 16 waves x 8KB (gate-tile 0 each)
  __shared__ unsigned short hs[2][16*H2_];    // 2 x 8 KB, chunk ch=s*32+k/8, swz ^(s&7)
  int tid = threadIdx.x;
  int n0 = blockIdx.x * 16;
  int lane = tid & 63, wave = tid >> 6;
  int l15 = lane & 15, l4 = lane >> 4;
  int n = n0 + l15;
  float creg[4] = {0.f,0.f,0.f,0.f};
  {
    int ct0 = wave*4;
    #pragma unroll
    for(int it=0; it<8; it++){
      int c = it*64 + lane;
      int row = c >> 5;
      bf16x8 w8 = *(const bf16x8*)(Whb + (size_t)(ct0*16+row)*H2_ + (c&31)*8);
      *(bf16x8*)(wc + 8*((wave<<9) + (c ^ (row&7)))) = w8;
    }
  }
  const unsigned short* wptr[3];
  #pragma unroll
  for(int i=0;i<3;i++) wptr[i] = Whb + (size_t)((wave*4+1+i)*16 + l15)*H2_ + l4*8;
  const unsigned short* wc0 = wc + (wave<<12);
  __syncthreads();
  for(int t=0; t<L_; t++){
    bf16x4 xgv[4];
    #pragma unroll
    for(int i=0;i<4;i++){
      int jj = wave*16 + i*4 + l4;
      xgv[i] = *(const bf16x4*)(xgb + ((size_t)n*L_ + t)*G4_ + jj*4);
    }
    f32x4 acc[4] = {};
    if(t > 0){
      const unsigned short* hbuf = hs[(t+1)&1];
      bf16x8 hfr[8];
      #pragma unroll
      for(int kk=0; kk<8; kk++){
        int ch = l15*32 + kk*4 + l4;
        hfr[kk] = *(const bf16x8*)(hbuf + 8*(ch ^ (l15&7)));
      }
      #pragma unroll
      for(int kk=0; kk<8; kk++){
        bf16x8 wfr[4];
        wfr[0] = *(const bf16x8*)(wc0 + 8*((l15*32 + kk*4 + l4) ^ (l15&7)));
        #pragma unroll
        for(int i=0;i<3;i++) wfr[1+i] = *(const bf16x8*)(wptr[i] + kk*32);
        #pragma unroll
        for(int i=0;i<4;i++)
          acc[i] = __builtin_amdgcn_mfma_f32_16x16x32_bf16(wfr[i], hfr[kk], acc[i], 0,0,0);
      }
    }
    unsigned short* hout = hs[t&1];
    #pragma unroll
    for(int i=0;i<4;i++){
      int jj = wave*16 + i*4 + l4;
      float gi = acc[i][0] + b2f((unsigned short)xgv[i][0]);
      float gf = acc[i][1] + b2f((unsigned short)xgv[i][1]);
      float gg = acc[i][2] + b2f((unsigned short)xgv[i][2]);
      float go = acc[i][3] + b2f((unsigned short)xgv[i][3]);
      float cnew = sigf_fast(gf)*creg[i] + sigf_fast(gi)*tanh_fast(gg);
      creg[i] = cnew;
      float hnew = sigf_fast(go)*tanh_fast(cnew);
      Y[((size_t)n*L_ + t)*H2_ + jj] = hnew;
      int ch = l15*32 + (jj>>3);
      *(unsigned short*)((char*)hout + 16*(ch ^ (l15&7)) + (jj&7)*2) = f2b(hnew);
    }
    __syncthreads();
  }
}

// ---------------- fused h_agg + gate (uhismm must precede) ----------------
__global__ void k_hagg_gate(const float* __restrict__ y1, const float* __restrict__ uhish,
                            const float* __restrict__ g1w, const float* __restrict__ g1b,
                            const float* __restrict__ g2w, const float* __restrict__ g2b,
                            float* __restrict__ hagg, unsigned short* __restrict__ haggb,
                            float* __restrict__ gate){
  int n = blockIdx.x; int jj = threadIdx.x;   // 256
  float s=0.f;
  for(int t=0;t<L_;t++) s += y1[((long)n*L_+t)*H2_ + jj];
  float v = tanhf(s);
  hagg[n*H2_+jj] = v;
  haggb[n*H2_+jj] = f2b(v);
  __shared__ float red[256];
  red[jj] = uhish[n*H2_+jj]*g1w[jj] + v*g2w[jj];
  __syncthreads();
  for(int o=128;o>0;o>>=1){ if(jj<o) red[jj]+=red[jj+o]; __syncthreads(); }
  if(jj==0) gate[n] = 1.f/(1.f+expf(-(red[0]+g1b[0]+g2b[0])));
}

// ---------------- fused softmax + blend, single logits pass (exp cached in LDS) ----------------
__global__ __launch_bounds__(512) void k_softmax_out(const float* __restrict__ logits,
    const float* __restrict__ gate, const float* __restrict__ uHis, float* __restrict__ out){
  __shared__ float pe[NIT_];                  // 80 KB exp cache
  __shared__ float red[512];
  __shared__ float mm, ss;
  int n = blockIdx.x; int t = threadIdx.x;    // 512
  const float* row = &logits[(long)n*NIT_];
  float m = -3.4e38f;
  for(int i=t;i<NIT_;i+=512) m = fmaxf(m, row[i]);
  red[t]=m; __syncthreads();
  for(int o=256;o>0;o>>=1){ if(t<o) red[t]=fmaxf(red[t],red[t+o]); __syncthreads(); }
  if(t==0) mm = red[0];
  __syncthreads();
  float s=0.f;
  for(int i=t;i<NIT_;i+=512){
    float e = __expf(row[i]-mm);
    pe[i] = e;
    s += e;
  }
  __syncthreads();
  red[t]=s; __syncthreads();
  for(int o=256;o>0;o>>=1){ if(t<o) red[t]+=red[t+o]; __syncthreads(); }
  if(t==0) ss = red[0];
  __syncthreads();
  float g = gate[n];
  float* orow = out + (long)n*NIT_;
  const float* urow = uHis + (long)n*NIT_;
  for(int i=t;i<NIT_;i+=512){
    float p = pe[i]/ss;
    orow[i] = g*p + (1.f-g)*urow[i];
  }
}

extern "C" void kernel_launch(void* const* d_in, const int* in_sizes, int n_in,
                              void* d_out, int out_size, void* d_ws, size_t ws_size,
                              hipStream_t stream) {
  const int*   seq     = (const int*)  d_in[0];
  const float* uHis    = (const float*)d_in[1];
  const float* itemEmb = (const float*)d_in[2];
  const float* fc1_w   = (const float*)d_in[3];
  const float* fc1_b   = (const float*)d_in[4];
  const float* aspProju= (const float*)d_in[5];
  const float* aspProji= (const float*)d_in[6];
  const float* dh_w    = (const float*)d_in[7];
  const float* dh_b    = (const float*)d_in[8];
  const float* wih0    = (const float*)d_in[9];
  const float* whh0    = (const float*)d_in[10];
  const float* bih0    = (const float*)d_in[11];
  const float* bhh0    = (const float*)d_in[12];
  const float* wih1    = (const float*)d_in[13];
  const float* whh1    = (const float*)d_in[14];
  const float* bih1    = (const float*)d_in[15];
  const float* bhh1    = (const float*)d_in[16];
  const float* out_w   = (const float*)d_in[17];
  const float* out_b   = (const float*)d_in[18];
  const float* his_w   = (const float*)d_in[19];
  const float* his_b   = (const float*)d_in[20];
  const float* g1_w    = (const float*)d_in[21];
  const float* g1_b    = (const float*)d_in[22];
  const float* g2_w    = (const float*)d_in[23];
  const float* g2_b    = (const float*)d_in[24];

  float* ws = (float*)d_ws;
  float* embs = ws + 0;            // 6,553,600   (reused as logits later)
  float* cub  = ws + 6553600;      // 6,553,600   (ebh bf16 shadow; reused as xgb bf16 later)
  float* na   = ws + 13107200;     // 5,242,880
  float* x    = ws + 18350080;     // 1,310,720   (reused as haggb after xg0)
  float* y0   = ws + 19660800;     // 1,310,720
  float* y1   = ws + 20971520;     // 1,310,720
  float* eb   = ws + 22282240;     //   655,360
  float* e2   = ws + 22937600;     //   655,360
  float* ua   = ws + 23855104;     //   131,072
  float* projT= ws + 23986176;     //    65,536  (holds projb bf16)
  float* wp0  = ws + 24051712;     //   262,144
  float* whp0 = ws + 24313856;     //   262,144  (bf16 permuted whh0)
  float* wp1  = ws + 24576000;     //   262,144
  float* whp1 = ws + 24838144;     //   262,144  (bf16 permuted whh1)
  float* bp0  = ws + 25100288;     //     1,024
  float* bp1  = ws + 25101312;     //     1,024
  float* uemb = ws + 25167872;     //       256
  float* sqb  = ws + 25168128;     //     1,024
  int*   nbr  = (int*)(ws + 25169152); // 15,360 ints
  float* uhish= ws + 25184512;     //    65,536
  float* hagg = ws + 25250048;     //    65,536
  float* gateb =ws + 25316096;     //       256
  float* logits = embs;            // reuse
  unsigned short* ebh   = (unsigned short*)cub;   // bf16 shadow (inside cub slot)
  unsigned short* xgb   = (unsigned short*)cub;   // bf16 xg (ebh dead after k_uimm)
  unsigned short* projb = (unsigned short*)projT; // bf16 (inside projT slot)
  unsigned short* haggb = (unsigned short*)x;     // bf16 hagg (x dead after xg0)
  unsigned short* whb0  = (unsigned short*)whp0;  // bf16 permuted whh0
  unsigned short* whb1  = (unsigned short*)whp1;  // bf16 permuted whh1

  // 1. fused gather + EB (fp32 + bf16 shadow + b-sum)
  k_gather2<<<NL_, D_, 0, stream>>>(seq, itemEmb, embs, ebh, eb);
  // 2. fc1 -> u_embs
  k_fc1<<<N_, 256, 0, stream>>>(embs, fc1_w, fc1_b, uemb);
  // 3. fused uA + sq
  k_uasq<<<ASP_*N_, 128, 0, stream>>>(uemb, aspProju, ua, sqb);
  // 4. fused dist + top-k
  k_disttopk<<<dim3(N_,ASP_), 256, 0, stream>>>(ua, sqb, nbr);
  // 5. E2 = EB @ dh_w^T
  k_gemm<<<dim3(2, 80, 1), 256, 0, stream>>>(eb, dh_w, e2, nullptr, NL_, H_, D_, D_, 0);
  // 6. fused prep (LSTM permutes + biases + projb)
  k_prep<<<4360, 256, 0, stream>>>(wih0, whh0, wih1, whh1, bih0, bhh0, bih1, bhh1,
                                   aspProji, wp0, whb0, wp1, whb1, bp0, bp1, projb);
  // 7. fused UI stage
  k_uimm<<<dim3(NL_/8, ASP_), 256, 0, stream>>>(ebh, projb, na);
  // 8. PI (neighbor sums)
  k_pi<<<dim3(N_,ASP_), H_, 0, stream>>>(e2, nbr, dh_b, na);
  // 9. x = flat max-4
  k_xmax<<<(N_*L_*H2_+255)/256, 256, 0, stream>>>(na, x);
  // 10. xg0 = x @ wp0^T + bp0 : bf16 MFMA, bf16 output
  k_xgmm<<<dim3(16,80), 256, 0, stream>>>(x, wp0, bp0, xgb);
  // 11. LSTM layer 0 (r15 structure)
  k_lstm_layer<<<16, 1024, 0, stream>>>(whb0, xgb, y0);
  // 12. xg1 = y0 @ wp1^T + bp1
  k_xgmm<<<dim3(16,80), 256, 0, stream>>>(y0, wp1, bp1, xgb);
  // 13. LSTM layer 1
  k_lstm_layer<<<16, 1024, 0, stream>>>(whb1, xgb, y1);
  // 14. uHis_h = uHis @ his_w^T + his_b : bf16 MFMA split-K
  hipMemsetAsync(uhish, 0, N_*H2_*sizeof(float), stream);
  k_uhismm<<<dim3(4,4,25), 256, 0, stream>>>(uHis, his_w, his_b, uhish);
  // 15. fused h_agg + gate
  k_hagg_gate<<<N_, 256, 0, stream>>>(y1, uhish, g1_w, g1_b, g2_w, g2_b, hagg, haggb, gateb);
  // 16. logits = h_agg @ out_w^T + out_b (fp32 W cast in-register)
  k_logitsmm<<<625, 256, 0, stream>>>(haggb, out_w, out_b, logits);
  // 17. fused softmax + blend (single logits pass)
  k_softmax_out<<<N_, 512, 0, stream>>>(logits, gateb, uHis, (float*)d_out);
}

// Round 20
// 465.639 us; speedup vs baseline: 1.1218x; 1.0740x over previous
//
#include <hip/hip_runtime.h>
#include <math.h>

#define N_ 256
#define L_ 20
#define B_ 10
#define D_ 128
#define H_ 128
#define ASP_ 4
#define KK_ 16
#define NIT_ 20000
#define H2_ 256
#define G4_ 1024
#define LBD_ 25600
#define NL_ 5120
#define NLB_ 51200

typedef __attribute__((ext_vector_type(8))) short bf16x8;
typedef __attribute__((ext_vector_type(4))) short bf16x4;
typedef __attribute__((ext_vector_type(4))) float f32x4;

__device__ __forceinline__ float sigf_fast(float x){
  return __builtin_amdgcn_rcpf(1.0f + __expf(-x));
}
__device__ __forceinline__ float tanh_fast(float x){
  return 1.0f - 2.0f*__builtin_amdgcn_rcpf(__expf(2.0f*x) + 1.0f);
}
__device__ __forceinline__ unsigned short f2b(float f){
  unsigned int u = __float_as_uint(f);
  unsigned int r = (u + 0x7FFFu + ((u>>16)&1u)) >> 16;   // RNE
  return (unsigned short)r;
}
__device__ __forceinline__ float b2f(unsigned short b){
  return __uint_as_float(((unsigned int)b) << 16);
}

// ---------------- merged gather+EB (blocks 0..5119) + prep (blocks 5120..13839) ----------------
__global__ __launch_bounds__(128) void k_gprep(const int* __restrict__ seq,
    const float* __restrict__ itemEmb, float* __restrict__ embs,
    unsigned short* __restrict__ ebh, float* __restrict__ eb,
    const float* __restrict__ wih0, const float* __restrict__ whh0,
    const float* __restrict__ wih1, const float* __restrict__ whh1,
    const float* __restrict__ bih0, const float* __restrict__ bhh0,
    const float* __restrict__ bih1, const float* __restrict__ bhh1,
    const float* __restrict__ proji,
    float* __restrict__ wp0, unsigned short* __restrict__ whb0,
    float* __restrict__ wp1, unsigned short* __restrict__ whb1,
    float* __restrict__ bp0, float* __restrict__ bp1,
    unsigned short* __restrict__ projb){
  if(blockIdx.x < NL_){
    int nl = blockIdx.x;
    int d = threadIdx.x;
    float s = 0.f;
    #pragma unroll
    for(int b=0;b<B_;b++){
      int idx = seq[nl*B_ + b];
      float v = itemEmb[(size_t)idx*D_ + d];
      embs[(size_t)(nl*B_+b)*D_ + d] = v;
      ebh[(size_t)(nl*B_+b)*D_ + d] = f2b(v);
      s += v;
    }
    eb[(size_t)nl*D_ + d] = s;
  } else {
    int i = (blockIdx.x - NL_)*128 + threadIdx.x;
    if(i < 262144){
      int k=i%H2_, j=i/H2_, g=j/H2_, jj=j%H2_;
      wp0[(jj*4+g)*H2_+k] = wih0[i];
    } else if(i < 524288){
      int e=i-262144; int k=e%H2_, j=e/H2_, g=j/H2_, jj=j%H2_;
      whb0[(jj*4+g)*H2_+k] = f2b(whh0[e]);
    } else if(i < 786432){
      int e=i-524288; int k=e%H2_, j=e/H2_, g=j/H2_, jj=j%H2_;
      wp1[(jj*4+g)*H2_+k] = wih1[e];
    } else if(i < 1048576){
      int e=i-786432; int k=e%H2_, j=e/H2_, g=j/H2_, jj=j%H2_;
      whb1[(jj*4+g)*H2_+k] = f2b(whh1[e]);
    } else if(i < 1114112){
      int e=i-1048576; int h=e%H_, d=(e/H_)%D_, aa=e/(D_*H_);
      projb[(aa*H_+h)*D_+d] = f2b(proji[e]);
    } else if(i < 1115136){
      int j=i-1114112; int g=j/H2_, jj=j%H2_;
      bp0[jj*4+g] = bih0[j] + bhh0[j];
    } else if(i < 1116160){
      int j=i-1115136; int g=j/H2_, jj=j%H2_;
      bp1[jj*4+g] = bih1[j] + bhh1[j];
    }
  }
}

// ---------------- fc1: u[n] = dot(embs[n,:], fc1_w) + fc1_b ----------------
__global__ void k_fc1(const float* __restrict__ embs, const float* __restrict__ w,
                      const float* __restrict__ b, float* __restrict__ u){
  int n = blockIdx.x; int t = threadIdx.x;
  float s = 0.f;
  for (int i = t; i < LBD_; i += 256) s += embs[n*LBD_+i]*w[i];
  __shared__ float red[256];
  red[t]=s; __syncthreads();
  for (int o=128;o>0;o>>=1){ if(t<o) red[t]+=red[t+o]; __syncthreads(); }
  if(t==0) u[n]=red[0]+b[0];
}

// ---------------- fused uA + sq (libm tanh: kNN path stays bit-stable) ----------------
__global__ void k_uasq(const float* __restrict__ u, const float* __restrict__ proju,
                       float* __restrict__ ua, float* __restrict__ sq){
  int an = blockIdx.x;           // a*N_+n
  int h = threadIdx.x;           // 128
  int a = an / N_, n = an % N_;
  float v = tanhf(tanhf(u[n]*proju[a*H_+h]));
  ua[an*H_ + h] = v;
  __shared__ float red[128];
  red[h] = v*v; __syncthreads();
  for(int o=64;o>0;o>>=1){ if(h<o) red[h]+=red[h+o]; __syncthreads(); }
  if(h==0) sq[an]=red[0];
}

// ---------------- fused dist + top-16 + PI (needs e2 ready; bit-identical) ----------------
__global__ __launch_bounds__(256) void k_disttopk_pi(const float* __restrict__ ua,
    const float* __restrict__ sq, const float* __restrict__ e2,
    const float* __restrict__ dh_b, int* __restrict__ nbr, float* __restrict__ na){
  int n = blockIdx.x, a = blockIdx.y, m = threadIdx.x;  // 256 threads
  __shared__ float un[H_];
  __shared__ float row[N_];
  __shared__ int nbs[KK_-1];
  if(m < H_) un[m] = ua[(a*N_+n)*H_ + m];
  __syncthreads();
  const float* um = &ua[(a*N_+m)*H_];
  float dot=0.f;
  for(int h=0;h<H_;h++) dot += un[h]*um[h];
  float dval = sq[a*N_+n] + sq[a*N_+m] - 2.f*dot;
  if(m==n) dval = -1.0f;
  row[m] = dval;
  __syncthreads();
  if(m < 64){
    int lane = m;
    int wid = a*N_+n;
    float v[4]; int idx[4];
    #pragma unroll
    for(int j=0;j<4;j++){ int mm = lane*4 + j; v[j] = row[mm]; idx[j] = mm; }
    for(int k=0;k<KK_;k++){
      float bv = v[0]; int bi = idx[0];
      #pragma unroll
      for(int j=1;j<4;j++)
        if(v[j] < bv || (v[j]==bv && idx[j] < bi)){ bv=v[j]; bi=idx[j]; }
      float rv = bv; int ri = bi;
      #pragma unroll
      for(int o=32;o>0;o>>=1){
        float ov = __shfl_xor(rv, o, 64);
        int   oi = __shfl_xor(ri, o, 64);
        if(ov < rv || (ov==rv && oi < ri)){ rv=ov; ri=oi; }
      }
      if((ri>>2) == lane){ v[ri&3] = 3.4e38f; idx[ri&3] = 0x7fffffff; }
      if(k>0 && lane==0){ nbr[wid*(KK_-1)+(k-1)] = ri; nbs[k-1] = ri; }
    }
  }
  __syncthreads();
  if(m < H_){
    int h = m;
    float bias = (float)B_ * dh_b[h];
    for(int l=0;l<L_;l++){
      float s = bias;
      for(int k=0;k<KK_-1;k++) s += e2[(size_t)(nbs[k]*L_ + l)*H_ + h];
      na[((size_t)(n*ASP_+a)*L_ + l)*H2_ + H_ + h] = s;
    }
  }
}

// ---------------- fused UI stage: MFMA bf16 GEMM + tanh^2 + sum_b -> na[.., 0:128] ----------------
__global__ __launch_bounds__(256) void k_uimm(const unsigned short* __restrict__ ebh,
                                              const unsigned short* __restrict__ projb,
                                              float* __restrict__ na){
  __shared__ char smem[53248];
  unsigned short* As = (unsigned short*)smem;            // 80x128 bf16, swizzled 16B chunks
  unsigned short* Bs = (unsigned short*)(smem + 20480);  // 128x128 bf16, swizzled
  float*          Cs = (float*)smem;                     // 80x128 f32 (aliases As+Bs later)

  int mb = blockIdx.x;   // 0..639
  int a  = blockIdx.y;   // 0..3
  int tid = threadIdx.x;

  const unsigned short* asrc = ebh + (size_t)mb*10240;
  #pragma unroll
  for(int t=0;t<5;t++){
    int c = tid + t*256;
    int row = c >> 4;
    *(bf16x8*)(As + 8*(c ^ (row&7))) = *(const bf16x8*)(asrc + 8*c);
  }
  const unsigned short* bsrc = projb + a*16384;
  #pragma unroll
  for(int t=0;t<8;t++){
    int c = tid + t*256;
    int row = c >> 4;
    *(bf16x8*)(Bs + 8*(c ^ (row&7))) = *(const bf16x8*)(bsrc + 8*c);
  }
  __syncthreads();

  int lane = tid & 63, wave = tid >> 6;
  int l15 = lane & 15, l4 = lane >> 4;
  f32x4 acc[5][2] = {};
  #pragma unroll
  for(int kk=0;kk<4;kk++){
    bf16x8 bfr[2];
    #pragma unroll
    for(int tc=0;tc<2;tc++){
      int h = (wave*2+tc)*16 + l15;
      int c = h*16 + kk*4 + l4;
      bfr[tc] = *(const bf16x8*)(Bs + 8*(c ^ (h&7)));
    }
    #pragma unroll
    for(int tr=0;tr<5;tr++){
      int R = tr*16 + l15;
      int c = R*16 + kk*4 + l4;
      bf16x8 afr = *(const bf16x8*)(As + 8*(c ^ (R&7)));
      acc[tr][0] = __builtin_amdgcn_mfma_f32_16x16x32_bf16(afr, bfr[0], acc[tr][0], 0,0,0);
      acc[tr][1] = __builtin_amdgcn_mfma_f32_16x16x32_bf16(afr, bfr[1], acc[tr][1], 0,0,0);
    }
  }
  __syncthreads();

  #pragma unroll
  for(int tr=0;tr<5;tr++)
    #pragma unroll
    for(int tc=0;tc<2;tc++){
      int col = (wave*2+tc)*16 + l15;
      #pragma unroll
      for(int r=0;r<4;r++){
        int R = tr*16 + l4*4 + r;
        Cs[R*128 + col] = tanh_fast(tanh_fast(acc[tr][tc][r]));
      }
    }
  __syncthreads();

  #pragma unroll
  for(int t=0;t<4;t++){
    int oi = t*256 + tid;
    int g = oi >> 7, col = oi & 127;
    float s = 0.f;
    const float* p = Cs + g*1280 + col;
    #pragma unroll
    for(int b=0;b<10;b++) s += p[b*128];
    int nl = mb*8 + g;
    int n = nl/L_, l = nl%L_;
    na[((size_t)(n*ASP_+a)*L_ + l)*H2_ + col] = s;
  }
}

// ---------------- xg GEMM: bf16 MFMA, in-register cast, OUTPUT bf16 ----------------
__global__ __launch_bounds__(256) void k_xgmm(const float* __restrict__ A_,
    const float* __restrict__ W, const float* __restrict__ bias,
    unsigned short* __restrict__ Cb){
  __shared__ unsigned short As[2048];
  __shared__ unsigned short Bs[2048];
  int tid = threadIdx.x;
  int n0 = blockIdx.x*64, m0 = blockIdx.y*64;
  int row = tid & 63, q = tid >> 6;
  int lane = tid & 63, wave = tid >> 6;
  int l15 = lane & 15, l4 = lane >> 4;
  int wr = (wave>>1)*32, wc = (wave&1)*32;
  f32x4 acc[2][2] = {};
  for(int s=0;s<8;s++){
    int k0 = s*32 + q*8;
    {
      const float* pa = &A_[(size_t)(m0+row)*H2_ + k0];
      float4 a0 = *(const float4*)pa, a1 = *(const float4*)(pa+4);
      bf16x8 av;
      av[0]=f2b(a0.x); av[1]=f2b(a0.y); av[2]=f2b(a0.z); av[3]=f2b(a0.w);
      av[4]=f2b(a1.x); av[5]=f2b(a1.y); av[6]=f2b(a1.z); av[7]=f2b(a1.w);
      *(bf16x8*)(As + 8*tid) = av;
      const float* pb = &W[(size_t)(n0+row)*H2_ + k0];
      float4 b0 = *(const float4*)pb, b1 = *(const float4*)(pb+4);
      bf16x8 bv;
      bv[0]=f2b(b0.x); bv[1]=f2b(b0.y); bv[2]=f2b(b0.z); bv[3]=f2b(b0.w);
      bv[4]=f2b(b1.x); bv[5]=f2b(b1.y); bv[6]=f2b(b1.z); bv[7]=f2b(b1.w);
      *(bf16x8*)(Bs + 8*tid) = bv;
    }
    __syncthreads();
    bf16x8 afr[2], bfr[2];
    #pragma unroll
    for(int mt=0;mt<2;mt++) afr[mt] = *(const bf16x8*)(As + 8*(l4*64 + wr + mt*16 + l15));
    #pragma unroll
    for(int nt=0;nt<2;nt++) bfr[nt] = *(const bf16x8*)(Bs + 8*(l4*64 + wc + nt*16 + l15));
    #pragma unroll
    for(int mt=0;mt<2;mt++)
      #pragma unroll
      for(int nt=0;nt<2;nt++)
        acc[mt][nt] = __builtin_amdgcn_mfma_f32_16x16x32_bf16(afr[mt], bfr[nt], acc[mt][nt], 0,0,0);
    __syncthreads();
  }
  #pragma unroll
  for(int mt=0;mt<2;mt++)
    #pragma unroll
    for(int nt=0;nt<2;nt++){
      int col = n0 + wc + nt*16 + l15;
      float bs = bias[col];
      #pragma unroll
      for(int r=0;r<4;r++){
        int rw = m0 + wr + mt*16 + l4*4 + r;
        Cb[(size_t)rw*G4_ + col] = f2b(acc[mt][nt][r] + bs);
      }
    }
}

// ---------------- merged LSTM layer 0 (blocks 0..15) + uhismm (blocks 16..115) ----------------
// Pointer-array initializer removed (r19 compile fix): hs base selected via runtime
// arithmetic on a char* base. Math identical to r15/r18 structures.
__global__ __launch_bounds__(1024) void k_lstm0u(
    const unsigned short* __restrict__ Whb, const unsigned short* __restrict__ xgb,
    float* __restrict__ Y,
    const float* __restrict__ U, const float* __restrict__ W,
    const float* __restrict__ bias, float* __restrict__ C){
  __shared__ char smem[147456];   // LSTM: wc 128KB + hs 2x8KB ; uhismm: 4 x 8KB
  int tid = threadIdx.x;
  if(blockIdx.x < 16){
    unsigned short* wc = (unsigned short*)smem;
    char* hbase = smem + 131072;            // hs[0] at +0, hs[1] at +8192
    int n0 = blockIdx.x * 16;
    int lane = tid & 63, wave = tid >> 6;
    int l15 = lane & 15, l4 = lane >> 4;
    int n = n0 + l15;
    float creg[4] = {0.f,0.f,0.f,0.f};
    {
      int ct0 = wave*4;
      #pragma unroll
      for(int it=0; it<8; it++){
        int c = it*64 + lane;
        int row = c >> 5;
        bf16x8 w8 = *(const bf16x8*)(Whb + (size_t)(ct0*16+row)*H2_ + (c&31)*8);
        *(bf16x8*)(wc + 8*((wave<<9) + (c ^ (row&7)))) = w8;
      }
    }
    const unsigned short* wptr[3];
    #pragma unroll
    for(int i=0;i<3;i++) wptr[i] = Whb + (size_t)((wave*4+1+i)*16 + l15)*H2_ + l4*8;
    const unsigned short* wc0 = wc + (wave<<12);
    __syncthreads();
    for(int t=0; t<L_; t++){
      bf16x4 xgv[4];
      #pragma unroll
      for(int i=0;i<4;i++){
        int jj = wave*16 + i*4 + l4;
        xgv[i] = *(const bf16x4*)(xgb + ((size_t)n*L_ + t)*G4_ + jj*4);
      }
      f32x4 acc[4] = {};
      if(t > 0){
        const unsigned short* hbuf = (const unsigned short*)(hbase + ((t+1)&1)*8192);
        bf16x8 hfr[8];
        #pragma unroll
        for(int kk=0; kk<8; kk++){
          int ch = l15*32 + kk*4 + l4;
          hfr[kk] = *(const bf16x8*)(hbuf + 8*(ch ^ (l15&7)));
        }
        #pragma unroll
        for(int kk=0; kk<8; kk++){
          bf16x8 wfr[4];
          wfr[0] = *(const bf16x8*)(wc0 + 8*((l15*32 + kk*4 + l4) ^ (l15&7)));
          #pragma unroll
          for(int i=0;i<3;i++) wfr[1+i] = *(const bf16x8*)(wptr[i] + kk*32);
          #pragma unroll
          for(int i=0;i<4;i++)
            acc[i] = __builtin_amdgcn_mfma_f32_16x16x32_bf16(wfr[i], hfr[kk], acc[i], 0,0,0);
        }
      }
      char* hout = hbase + (t&1)*8192;
      #pragma unroll
      for(int i=0;i<4;i++){
        int jj = wave*16 + i*4 + l4;
        float gi = acc[i][0] + b2f((unsigned short)xgv[i][0]);
        float gf = acc[i][1] + b2f((unsigned short)xgv[i][1]);
        float gg = acc[i][2] + b2f((unsigned short)xgv[i][2]);
        float go = acc[i][3] + b2f((unsigned short)xgv[i][3]);
        float cnew = sigf_fast(gf)*creg[i] + sigf_fast(gi)*tanh_fast(gg);
        creg[i] = cnew;
        float hnew = sigf_fast(go)*tanh_fast(cnew);
        Y[((size_t)n*L_ + t)*H2_ + jj] = hnew;
        int ch = l15*32 + (jj>>3);
        *(unsigned short*)(hout + 16*(ch ^ (l15&7)) + (jj&7)*2) = f2b(hnew);
      }
      __syncthreads();
    }
  } else {
    // uhismm path: subgroup sub handles original sub-block s_id
    int sub = tid >> 8;                 // 0..3
    int t2  = tid & 255;
    int s_id = (blockIdx.x - 16)*4 + sub;   // 0..399
    int n0 = (s_id & 3)*64;
    int m0 = ((s_id>>2) & 3)*64;
    int kz = s_id >> 4;                 // 0..24
    int kb0 = kz*800;
    unsigned short* As = (unsigned short*)(smem + sub*8192);
    unsigned short* Bs = (unsigned short*)(smem + sub*8192 + 4096);
    int row = t2 & 63, q = t2 >> 6;
    int lane = t2 & 63, wave = t2 >> 6;
    int l15 = lane & 15, l4 = lane >> 4;
    int wr = (wave>>1)*32, wc2 = (wave&1)*32;
    f32x4 acc[2][2] = {};
    for(int s=0;s<25;s++){
      int k0 = kb0 + s*32 + q*8;
      {
        const float* pa = &U[(size_t)(m0+row)*NIT_ + k0];
        float4 a0 = *(const float4*)pa, a1 = *(const float4*)(pa+4);
        bf16x8 av;
        av[0]=f2b(a0.x); av[1]=f2b(a0.y); av[2]=f2b(a0.z); av[3]=f2b(a0.w);
        av[4]=f2b(a1.x); av[5]=f2b(a1.y); av[6]=f2b(a1.z); av[7]=f2b(a1.w);
        *(bf16x8*)(As + 8*t2) = av;
        const float* pb = &W[(size_t)(n0+row)*NIT_ + k0];
        float4 b0 = *(const float4*)pb, b1 = *(const float4*)(pb+4);
        bf16x8 bv;
        bv[0]=f2b(b0.x); bv[1]=f2b(b0.y); bv[2]=f2b(b0.z); bv[3]=f2b(b0.w);
        bv[4]=f2b(b1.x); bv[5]=f2b(b1.y); bv[6]=f2b(b1.z); bv[7]=f2b(b1.w);
        *(bf16x8*)(Bs + 8*t2) = bv;
      }
      __syncthreads();
      bf16x8 afr[2], bfr[2];
      #pragma unroll
      for(int mt=0;mt<2;mt++) afr[mt] = *(const bf16x8*)(As + 8*(l4*64 + wr + mt*16 + l15));
      #pragma unroll
      for(int nt=0;nt<2;nt++) bfr[nt] = *(const bf16x8*)(Bs + 8*(l4*64 + wc2 + nt*16 + l15));
      #pragma unroll
      for(int mt=0;mt<2;mt++)
        #pragma unroll
        for(int nt=0;nt<2;nt++)
          acc[mt][nt] = __builtin_amdgcn_mfma_f32_16x16x32_bf16(afr[mt], bfr[nt], acc[mt][nt], 0,0,0);
      __syncthreads();
    }
    #pragma unroll
    for(int mt=0;mt<2;mt++)
      #pragma unroll
      for(int nt=0;nt<2;nt++){
        int col = n0 + wc2 + nt*16 + l15;
        #pragma unroll
        for(int r=0;r<4;r++){
          int rw = m0 + wr + mt*16 + l4*4 + r;
          float v = acc[mt][nt][r];
          if(kz==0) v += bias[col];
          atomicAdd(&C[rw*H2_ + col], v);
        }
      }
  }
}

// ---------------- fused LSTM layer (r15 structure; layer 1) ----------------
__global__ __launch_bounds__(1024) void k_lstm_layer(
    const unsigned short* __restrict__ Whb,
    const unsigned short* __restrict__ xgb,
    float* __restrict__ Y){
  __shared__ unsigned short wc[65536];
  __shared__ unsigned short hs[2][16*H2_];
  int tid = threadIdx.x;
  int n0 = blockIdx.x * 16;
  int lane = tid & 63, wave = tid >> 6;
  int l15 = lane & 15, l4 = lane >> 4;
  int n = n0 + l15;
  float creg[4] = {0.f,0.f,0.f,0.f};
  {
    int ct0 = wave*4;
    #pragma unroll
    for(int it=0; it<8; it++){
      int c = it*64 + lane;
      int row = c >> 5;
      bf16x8 w8 = *(const bf16x8*)(Whb + (size_t)(ct0*16+row)*H2_ + (c&31)*8);
      *(bf16x8*)(wc + 8*((wave<<9) + (c ^ (row&7)))) = w8;
    }
  }
  const unsigned short* wptr[3];
  #pragma unroll
  for(int i=0;i<3;i++) wptr[i] = Whb + (size_t)((wave*4+1+i)*16 + l15)*H2_ + l4*8;
  const unsigned short* wc0 = wc + (wave<<12);
  __syncthreads();
  for(int t=0; t<L_; t++){
    bf16x4 xgv[4];
    #pragma unroll
    for(int i=0;i<4;i++){
      int jj = wave*16 + i*4 + l4;
      xgv[i] = *(const bf16x4*)(xgb + ((size_t)n*L_ + t)*G4_ + jj*4);
    }
    f32x4 acc[4] = {};
    if(t > 0){
      const unsigned short* hbuf = hs[(t+1)&1];
      bf16x8 hfr[8];
      #pragma unroll
      for(int kk=0; kk<8; kk++){
        int ch = l15*32 + kk*4 + l4;
        hfr[kk] = *(const bf16x8*)(hbuf + 8*(ch ^ (l15&7)));
      }
      #pragma unroll
      for(int kk=0; kk<8; kk++){
        bf16x8 wfr[4];
        wfr[0] = *(const bf16x8*)(wc0 + 8*((l15*32 + kk*4 + l4) ^ (l15&7)));
        #pragma unroll
        for(int i=0;i<3;i++) wfr[1+i] = *(const bf16x8*)(wptr[i] + kk*32);
        #pragma unroll
        for(int i=0;i<4;i++)
          acc[i] = __builtin_amdgcn_mfma_f32_16x16x32_bf16(wfr[i], hfr[kk], acc[i], 0,0,0);
      }
    }
    unsigned short* hout = hs[t&1];
    #pragma unroll
    for(int i=0;i<4;i++){
      int jj = wave*16 + i*4 + l4;
      float gi = acc[i][0] + b2f((unsigned short)xgv[i][0]);
      float gf = acc[i][1] + b2f((unsigned short)xgv[i][1]);
      float gg = acc[i][2] + b2f((unsigned short)xgv[i][2]);
      float go = acc[i][3] + b2f((unsigned short)xgv[i][3]);
      float cnew = sigf_fast(gf)*creg[i] + sigf_fast(gi)*tanh_fast(gg);
      creg[i] = cnew;
      float hnew = sigf_fast(go)*tanh_fast(cnew);
      Y[((size_t)n*L_ + t)*H2_ + jj] = hnew;
      int ch = l15*32 + (jj>>3);
      *(unsigned short*)((char*)hout + 16*(ch ^ (l15&7)) + (jj&7)*2) = f2b(hnew);
    }
    __syncthreads();
  }
}

// ---------------- logits: bf16 MFMA, fp32 out_w cast in-register ----------------
__global__ __launch_bounds__(256) void k_logitsmm(const unsigned short* __restrict__ Ab,
    const float* __restrict__ Wf, const float* __restrict__ bias,
    float* __restrict__ C){
  int n0 = blockIdx.x*32;
  int tid = threadIdx.x;
  int lane = tid & 63, wave = tid >> 6;
  int l15 = lane & 15, l4 = lane >> 4;
  f32x4 acc[4][2] = {};
  #pragma unroll
  for(int kk=0;kk<8;kk++){
    int k0 = kk*32 + l4*8;
    bf16x8 bfr[2];
    #pragma unroll
    for(int nt=0;nt<2;nt++){
      const float* pb = &Wf[(size_t)(n0 + nt*16 + l15)*H2_ + k0];
      float4 b0 = *(const float4*)pb, b1 = *(const float4*)(pb+4);
      bf16x8 bv;
      bv[0]=f2b(b0.x); bv[1]=f2b(b0.y); bv[2]=f2b(b0.z); bv[3]=f2b(b0.w);
      bv[4]=f2b(b1.x); bv[5]=f2b(b1.y); bv[6]=f2b(b1.z); bv[7]=f2b(b1.w);
      bfr[nt] = bv;
    }
    #pragma unroll
    for(int mt=0;mt<4;mt++){
      bf16x8 afr = *(const bf16x8*)(Ab + (size_t)(wave*64 + mt*16 + l15)*H2_ + k0);
      acc[mt][0] = __builtin_amdgcn_mfma_f32_16x16x32_bf16(afr, bfr[0], acc[mt][0], 0,0,0);
      acc[mt][1] = __builtin_amdgcn_mfma_f32_16x16x32_bf16(afr, bfr[1], acc[mt][1], 0,0,0);
    }
  }
  #pragma unroll
  for(int mt=0;mt<4;mt++)
    #pragma unroll
    for(int nt=0;nt<2;nt++){
      int col = n0 + nt*16 + l15;
      float bs = bias[col];
      #pragma unroll
      for(int r=0;r<4;r++){
        int row = wave*64 + mt*16 + l4*4 + r;
        C[(size_t)row*NIT_ + col] = acc[mt][nt][r] + bs;
      }
    }
}

// ---------------- generic fp32 NT GEMM (E2 only) ----------------
__global__ __launch_bounds__(256) void k_gemm(const float* __restrict__ A, const float* __restrict__ W,
    float* __restrict__ C, const float* __restrict__ bias,
    int M, int Nn, int K, int kchunk, int atomic_mode){
  __shared__ float As[64][17];
  __shared__ float Ws[64][17];
  int tid = threadIdx.x;
  int tx = tid & 15, ty = tid >> 4;
  int m0 = blockIdx.y*64, n0 = blockIdx.x*64;
  int kb0 = blockIdx.z*kchunk;
  int kend = kb0 + kchunk; if(kend > K) kend = K;
  float acc[4][4] = {};
  int lrow = tid >> 2;
  int lc4 = (tid & 3) * 4;
  for(int kb = kb0; kb < kend; kb += 16){
    {
      int gr = m0 + lrow;
      float4 v = make_float4(0,0,0,0);
      if(gr < M) v = *(const float4*)&A[(long)gr*K + kb + lc4];
      As[lrow][lc4+0]=v.x; As[lrow][lc4+1]=v.y; As[lrow][lc4+2]=v.z; As[lrow][lc4+3]=v.w;
      int gw = n0 + lrow;
      float4 u = make_float4(0,0,0,0);
      if(gw < Nn) u = *(const float4*)&W[(long)gw*K + kb + lc4];
      Ws[lrow][lc4+0]=u.x; Ws[lrow][lc4+1]=u.y; Ws[lrow][lc4+2]=u.z; Ws[lrow][lc4+3]=u.w;
    }
    __syncthreads();
    for(int k=0;k<16;k++){
      float av[4], wv[4];
      #pragma unroll
      for(int r=0;r<4;r++) av[r]=As[ty*4+r][k];
      #pragma unroll
      for(int c=0;c<4;c++) wv[c]=Ws[tx*4+c][k];
      #pragma unroll
      for(int r=0;r<4;r++)
        #pragma unroll
        for(int c=0;c<4;c++) acc[r][c] += av[r]*wv[c];
    }
    __syncthreads();
  }
  for(int r=0;r<4;r++){
    int row = m0 + ty*4 + r; if(row >= M) continue;
    for(int c=0;c<4;c++){
      int col = n0 + tx*4 + c; if(col >= Nn) continue;
      float v = acc[r][c];
      if(bias && blockIdx.z==0) v += bias[col];
      if(atomic_mode) atomicAdd(&C[(long)row*Nn+col], v);
      else C[(long)row*Nn+col] = v;
    }
  }
}

// ---------------- x: flat reinterpret max over 4 consecutive ----------------
__global__ void k_xmax(const float* __restrict__ na, float* __restrict__ x){
  int i = blockIdx.x*blockDim.x + threadIdx.x;
  if(i >= N_*L_*H2_) return;
  int n = i / (L_*H2_);
  int j = i % (L_*H2_);
  const float* p = &na[(long)n*ASP_*L_*H2_ + 4*j];
  x[i] = fmaxf(fmaxf(p[0],p[1]), fmaxf(p[2],p[3]));
}

// ---------------- fused h_agg + gate ----------------
__global__ void k_hagg_gate(const float* __restrict__ y1, const float* __restrict__ uhish,
                            const float* __restrict__ g1w, const float* __restrict__ g1b,
                            const float* __restrict__ g2w, const float* __restrict__ g2b,
                            float* __restrict__ hagg, unsigned short* __restrict__ haggb,
                            float* __restrict__ gate){
  int n = blockIdx.x; int jj = threadIdx.x;   // 256
  float s=0.f;
  for(int t=0;t<L_;t++) s += y1[((long)n*L_+t)*H2_ + jj];
  float v = tanhf(s);
  hagg[n*H2_+jj] = v;
  haggb[n*H2_+jj] = f2b(v);
  __shared__ float red[256];
  red[jj] = uhish[n*H2_+jj]*g1w[jj] + v*g2w[jj];
  __syncthreads();
  for(int o=128;o>0;o>>=1){ if(jj<o) red[jj]+=red[jj+o]; __syncthreads(); }
  if(jj==0) gate[n] = 1.f/(1.f+expf(-(red[0]+g1b[0]+g2b[0])));
}

// ---------------- fused softmax + blend, single logits pass ----------------
__global__ __launch_bounds__(512) void k_softmax_out(const float* __restrict__ logits,
    const float* __restrict__ gate, const float* __restrict__ uHis, float* __restrict__ out){
  __shared__ float pe[NIT_];                  // 80 KB exp cache
  __shared__ float red[512];
  __shared__ float mm, ss;
  int n = blockIdx.x; int t = threadIdx.x;    // 512
  const float* row = &logits[(long)n*NIT_];
  float m = -3.4e38f;
  for(int i=t;i<NIT_;i+=512) m = fmaxf(m, row[i]);
  red[t]=m; __syncthreads();
  for(int o=256;o>0;o>>=1){ if(t<o) red[t]=fmaxf(red[t],red[t+o]); __syncthreads(); }
  if(t==0) mm = red[0];
  __syncthreads();
  float s=0.f;
  for(int i=t;i<NIT_;i+=512){
    float e = __expf(row[i]-mm);
    pe[i] = e;
    s += e;
  }
  __syncthreads();
  red[t]=s; __syncthreads();
  for(int o=256;o>0;o>>=1){ if(t<o) red[t]+=red[t+o]; __syncthreads(); }
  if(t==0) ss = red[0];
  __syncthreads();
  float g = gate[n];
  float* orow = out + (long)n*NIT_;
  const float* urow = uHis + (long)n*NIT_;
  for(int i=t;i<NIT_;i+=512){
    float p = pe[i]/ss;
    orow[i] = g*p + (1.f-g)*urow[i];
  }
}

extern "C" void kernel_launch(void* const* d_in, const int* in_sizes, int n_in,
                              void* d_out, int out_size, void* d_ws, size_t ws_size,
                              hipStream_t stream) {
  const int*   seq     = (const int*)  d_in[0];
  const float* uHis    = (const float*)d_in[1];
  const float* itemEmb = (const float*)d_in[2];
  const float* fc1_w   = (const float*)d_in[3];
  const float* fc1_b   = (const float*)d_in[4];
  const float* aspProju= (const float*)d_in[5];
  const float* aspProji= (const float*)d_in[6];
  const float* dh_w    = (const float*)d_in[7];
  const float* dh_b    = (const float*)d_in[8];
  const float* wih0    = (const float*)d_in[9];
  const float* whh0    = (const float*)d_in[10];
  const float* bih0    = (const float*)d_in[11];
  const float* bhh0    = (const float*)d_in[12];
  const float* wih1    = (const float*)d_in[13];
  const float* whh1    = (const float*)d_in[14];
  const float* bih1    = (const float*)d_in[15];
  const float* bhh1    = (const float*)d_in[16];
  const float* out_w   = (const float*)d_in[17];
  const float* out_b   = (const float*)d_in[18];
  const float* his_w   = (const float*)d_in[19];
  const float* his_b   = (const float*)d_in[20];
  const float* g1_w    = (const float*)d_in[21];
  const float* g1_b    = (const float*)d_in[22];
  const float* g2_w    = (const float*)d_in[23];
  const float* g2_b    = (const float*)d_in[24];

  float* ws = (float*)d_ws;
  float* embs = ws + 0;            // 6,553,600   (reused as logits later)
  float* cub  = ws + 6553600;      // 6,553,600   (ebh bf16 shadow; reused as xgb bf16 later)
  float* na   = ws + 13107200;     // 5,242,880
  float* x    = ws + 18350080;     // 1,310,720   (reused as haggb after xg0)
  float* y0   = ws + 19660800;     // 1,310,720
  float* y1   = ws + 20971520;     // 1,310,720
  float* eb   = ws + 22282240;     //   655,360
  float* e2   = ws + 22937600;     //   655,360
  float* ua   = ws + 23855104;     //   131,072
  float* projT= ws + 23986176;     //    65,536  (holds projb bf16)
  float* wp0  = ws + 24051712;     //   262,144
  float* whp0 = ws + 24313856;     //   262,144  (bf16 permuted whh0)
  float* wp1  = ws + 24576000;     //   262,144
  float* whp1 = ws + 24838144;     //   262,144  (bf16 permuted whh1)
  float* bp0  = ws + 25100288;     //     1,024
  float* bp1  = ws + 25101312;     //     1,024
  float* uemb = ws + 25167872;     //       256
  float* sqb  = ws + 25168128;     //     1,024
  int*   nbr  = (int*)(ws + 25169152); // 15,360 ints
  float* uhish= ws + 25184512;     //    65,536
  float* hagg = ws + 25250048;     //    65,536
  float* gateb =ws + 25316096;     //       256
  float* logits = embs;            // reuse
  unsigned short* ebh   = (unsigned short*)cub;   // bf16 shadow (inside cub slot)
  unsigned short* xgb   = (unsigned short*)cub;   // bf16 xg (ebh dead after k_uimm)
  unsigned short* projb = (unsigned short*)projT; // bf16 (inside projT slot)
  unsigned short* haggb = (unsigned short*)x;     // bf16 hagg (x dead after xg0)
  unsigned short* whb0  = (unsigned short*)whp0;  // bf16 permuted whh0
  unsigned short* whb1  = (unsigned short*)whp1;  // bf16 permuted whh1

  // 1. merged gather+EB + prep
  k_gprep<<<NL_ + 8720, 128, 0, stream>>>(seq, itemEmb, embs, ebh, eb,
      wih0, whh0, wih1, whh1, bih0, bhh0, bih1, bhh1, aspProji,
      wp0, whb0, wp1, whb1, bp0, bp1, projb);
  // 2. fc1 -> u_embs
  k_fc1<<<N_, 256, 0, stream>>>(embs, fc1_w, fc1_b, uemb);
  // 3. fused uA + sq
  k_uasq<<<ASP_*N_, 128, 0, stream>>>(uemb, aspProju, ua, sqb);
  // 4. E2 = EB @ dh_w^T (before disttopk_pi which consumes e2)
  k_gemm<<<dim3(2, 80, 1), 256, 0, stream>>>(eb, dh_w, e2, nullptr, NL_, H_, D_, D_, 0);
  // 5. fused dist + top-k + PI
  k_disttopk_pi<<<dim3(N_,ASP_), 256, 0, stream>>>(ua, sqb, e2, dh_b, nbr, na);
  // 6. fused UI stage
  k_uimm<<<dim3(NL_/8, ASP_), 256, 0, stream>>>(ebh, projb, na);
  // 7. x = flat max-4
  k_xmax<<<(N_*L_*H2_+255)/256, 256, 0, stream>>>(na, x);
  // 8. xg0 = x @ wp0^T + bp0
  k_xgmm<<<dim3(16,80), 256, 0, stream>>>(x, wp0, bp0, xgb);
  // 9. merged LSTM layer 0 + uhismm (uhismm hidden under LSTM's 16-CU phase)
  (void)hipMemsetAsync(uhish, 0, N_*H2_*sizeof(float), stream);
  k_lstm0u<<<116, 1024, 0, stream>>>(whb0, xgb, y0, uHis, his_w, his_b, uhish);
  // 10. xg1 = y0 @ wp1^T + bp1
  k_xgmm<<<dim3(16,80), 256, 0, stream>>>(y0, wp1, bp1, xgb);
  // 11. LSTM layer 1
  k_lstm_layer<<<16, 1024, 0, stream>>>(whb1, xgb, y1);
  // 12. fused h_agg + gate
  k_hagg_gate<<<N_, 256, 0, stream>>>(y1, uhish, g1_w, g1_b, g2_w, g2_b, hagg, haggb, gateb);
  // 13. logits = h_agg @ out_w^T + out_b (fp32 W cast in-register)
  k_logitsmm<<<625, 256, 0, stream>>>(haggb, out_w, out_b, logits);
  // 14. fused softmax + blend
  k_softmax_out<<<N_, 512, 0, stream>>>(logits, gateb, uHis, (float*)d_out);
}